// Round 14
// baseline (1972.991 us; speedup 1.0000x reference)
//
#include <hip/hip_runtime.h>
#include <hip/hip_bf16.h>

#define NPTS 8192
#define NB 16
#define NS 1024
#define NK 32
#define NSAMP (NB*NS*NK)  // 524288
#define NTILE (NSAMP/16)  // 32768 sample-tiles of 16
#define EPSBN 1e-5f

// Chosen k-mapping for MFMA fragments (any consistent bijection works:
// it cancels between A and B; chosen so the D->B bridge is lane-local).
#define HK(Q, JJ) (4*(Q) + ((JJ)&3) + 16*((JJ)>>2))

typedef __attribute__((ext_vector_type(8))) short bf16x8;
typedef __attribute__((ext_vector_type(4))) float f32x4;

__device__ __forceinline__ short f2bf(float x) {
  union { __hip_bfloat16 h; short s; } u;
  u.h = __float2bfloat16(x);
  return u.s;
}

// monotone float->uint mapping (preserves order for min/max on unsigned).
// REQUIRED for kNN keys: self-distance rounds to tiny NEGATIVE floats; raw
// float bits as unsigned would sort them last (R6 bug).
__device__ __forceinline__ unsigned monof(float f) {
  unsigned u = __float_as_uint(f);
  return u ^ ((unsigned)((int)u >> 31) | 0x80000000u);
}

// ---------------------------------------------------------------------------
// Wave64 SINGLE-VALUE reductions via DPP. Each step fuses to ONE VALU op
// (v_max/min_u32 with DPP source modifier) — R12's paired (value,index)
// chain could NOT fuse (5 ops/step) and REGRESSED; do not reintroduce.
// Argmax/argmin = value chain, then masked-index min chain (exact
// smallest-index tie-break). Sequence: row_shr 1/2/4/8, row_bcast:15,
// row_bcast:31; lane 63 holds the result; readlane broadcasts.
// ---------------------------------------------------------------------------
__device__ __forceinline__ unsigned wave_max_u32(unsigned v) {
  unsigned t;
  t = (unsigned)__builtin_amdgcn_update_dpp(0, (int)v, 0x111, 0xf, 0xf, false); v = v > t ? v : t;
  t = (unsigned)__builtin_amdgcn_update_dpp(0, (int)v, 0x112, 0xf, 0xf, false); v = v > t ? v : t;
  t = (unsigned)__builtin_amdgcn_update_dpp(0, (int)v, 0x114, 0xf, 0xf, false); v = v > t ? v : t;
  t = (unsigned)__builtin_amdgcn_update_dpp(0, (int)v, 0x118, 0xf, 0xf, false); v = v > t ? v : t;
  t = (unsigned)__builtin_amdgcn_update_dpp(0, (int)v, 0x142, 0xa, 0xf, false); v = v > t ? v : t;
  t = (unsigned)__builtin_amdgcn_update_dpp(0, (int)v, 0x143, 0xc, 0xf, false); v = v > t ? v : t;
  return (unsigned)__builtin_amdgcn_readlane((int)v, 63);
}

__device__ __forceinline__ unsigned wave_min_u32(unsigned v) {
  unsigned t;
  t = (unsigned)__builtin_amdgcn_update_dpp(-1, (int)v, 0x111, 0xf, 0xf, false); v = v < t ? v : t;
  t = (unsigned)__builtin_amdgcn_update_dpp(-1, (int)v, 0x112, 0xf, 0xf, false); v = v < t ? v : t;
  t = (unsigned)__builtin_amdgcn_update_dpp(-1, (int)v, 0x114, 0xf, 0xf, false); v = v < t ? v : t;
  t = (unsigned)__builtin_amdgcn_update_dpp(-1, (int)v, 0x118, 0xf, 0xf, false); v = v < t ? v : t;
  t = (unsigned)__builtin_amdgcn_update_dpp(-1, (int)v, 0x142, 0xa, 0xf, false); v = v < t ? v : t;
  t = (unsigned)__builtin_amdgcn_update_dpp(-1, (int)v, 0x143, 0xc, 0xf, false); v = v < t ? v : t;
  return (unsigned)__builtin_amdgcn_readlane((int)v, 63);
}

// ---------------------------------------------------------------------------
// FPS v7: SAME single-batch structure as R13 (fastest: 855us) but 512 thr
// (8 waves = 2 waves/SIMD, 16 pts/lane). Per-SIMD scan ISSUE is invariant
// in wave count; the 2nd co-resident wave hides the DPP-chain + LDS-merge
// + centroid-read latencies that were fully exposed at 1 wave/SIMD.
// (NOT R9's regression: that coupled two independent batches via one
// barrier and read centroids from global. Here one batch, LDS centroid.)
// Selection math/rounding identical (no-FMA, monof, smallest-idx ties).
// ---------------------------------------------------------------------------
__global__ __launch_bounds__(512, 1) void fps_kernel(
    const float* __restrict__ xyz, float* __restrict__ newxyz, float* __restrict__ pp)
{
  __shared__ float sx[NPTS*3];                 // 96 KB
  __shared__ float cs[NS*3];                   // 12 KB centroid accum
  __shared__ unsigned long long kred[2][8];
  const int b = blockIdx.x, tid = threadIdx.x;
  const float* xb = xyz + (size_t)b * NPTS * 3;
  for (int i = tid; i < NPTS*3; i += 512) sx[i] = xb[i];
  __syncthreads();
  float px[16], py[16], pz[16], dist[16];
#pragma unroll
  for (int j = 0; j < 16; ++j) {
    const int i = tid + j*512;
    px[j] = sx[3*i]; py[j] = sx[3*i+1]; pz[j] = sx[3*i+2];
    dist[j] = 1e10f;
  }
  const int wid = tid >> 6;
  int far = 0;
  for (int t = 0; t < NS; ++t) {
    const float cx = sx[3*far], cy = sx[3*far+1], cz = sx[3*far+2];
    if (tid == 0) { cs[t*3] = cx; cs[t*3+1] = cy; cs[t*3+2] = cz; }
    float bv = -1.0f; int bj = 0;
#pragma unroll
    for (int j = 0; j < 16; ++j) {
      const float dx = __fsub_rn(px[j], cx);
      const float dy = __fsub_rn(py[j], cy);
      const float dz = __fsub_rn(pz[j], cz);
      const float d = __fadd_rn(__fadd_rn(__fmul_rn(dx,dx), __fmul_rn(dy,dy)), __fmul_rn(dz,dz));
      const float dj = fminf(dist[j], d);
      dist[j] = dj;
      const bool m = dj > bv;          // j ascending -> keeps smallest idx on tie
      bv = m ? dj : bv;
      bj = m ? j : bj;
    }
    const unsigned bi = (unsigned)(tid + bj*512);
    const unsigned mv = monof(bv);
    const unsigned vmax = wave_max_u32(mv);                    // wave max value
    const unsigned mbi = (mv == vmax) ? bi : 0xFFFFFFFFu;
    const unsigned bimin = wave_min_u32(mbi);                  // smallest idx on tie
    if ((tid & 63) == 0)
      kred[t & 1][wid] = ((unsigned long long)vmax << 32) | (unsigned)(8191 - bimin);
    __syncthreads();
    unsigned long long k0 = kred[t & 1][0], k1 = kred[t & 1][1];
    unsigned long long k2 = kred[t & 1][2], k3 = kred[t & 1][3];
    unsigned long long k4 = kred[t & 1][4], k5 = kred[t & 1][5];
    unsigned long long k6 = kred[t & 1][6], k7 = kred[t & 1][7];
    k0 = (k1 > k0) ? k1 : k0;
    k2 = (k3 > k2) ? k3 : k2;
    k4 = (k5 > k4) ? k5 : k4;
    k6 = (k7 > k6) ? k7 : k6;
    k0 = (k2 > k0) ? k2 : k0;
    k4 = (k6 > k4) ? k6 : k4;
    k0 = (k4 > k0) ? k4 : k0;           // max; tie -> larger (8191-idx) = smaller idx
    far = 8191 - (int)(k0 & 0xffffffffu);
  }
  // flush centroids (coalesced) and |p|^2 epilogue (knn's exact tt rounding)
  __syncthreads();
  float* nb = newxyz + (size_t)b * NS * 3;
  for (int idx = tid; idx < NS*3; idx += 512) nb[idx] = cs[idx];
  float* ppb = pp + (size_t)b * NPTS;
#pragma unroll
  for (int j = 0; j < 16; ++j) {
    const int i = tid + j*512;
    ppb[i] = __fadd_rn(__fadd_rn(__fmul_rn(px[j],px[j]), __fmul_rn(py[j],py[j])), __fmul_rn(pz[j],pz[j]));
  }
}

// ---------------------------------------------------------------------------
// kNN v4 (unchanged from R13): ONE WAVE per query, ZERO barriers,
// INCREMENTAL tournament + separate fused DPP chains.
// ---------------------------------------------------------------------------
__global__ __launch_bounds__(64) void knn_kernel(
    const float* __restrict__ xyz, const float* __restrict__ pp,
    const float* __restrict__ newxyz, int* __restrict__ gidx)
{
  __shared__ unsigned dm[NPTS];                // 32 KB -> 5 blocks/CU
  const int L = threadIdx.x;
  const int row = blockIdx.x;
  const int b = row >> 10;
  const float* xb = xyz + (size_t)b * NPTS * 3;
  const float* ppb = pp + (size_t)b * NPTS;
  const float qx = newxyz[(size_t)row*3+0];
  const float qy = newxyz[(size_t)row*3+1];
  const float qz = newxyz[(size_t)row*3+2];
  const float ss = __fadd_rn(__fadd_rn(__fmul_rn(qx,qx), __fmul_rn(qy,qy)), __fmul_rn(qz,qz));
  unsigned long long gk[8], gk2[8];
#pragma unroll
  for (int g = 0; g < 8; ++g) {
    unsigned long long best = ~0ull, sec = ~0ull;
#pragma unroll
    for (int m = 0; m < 16; ++m) {
      const int i = L + (g << 10) + (m << 6);
      const float tx = xb[3*i], ty = xb[3*i+1], tz = xb[3*i+2];
      const float tt = ppb[i];     // same bits as inline (x^2+y^2)+z^2
      const float dt = __fadd_rn(__fadd_rn(__fmul_rn(qx,tx), __fmul_rn(qy,ty)), __fmul_rn(qz,tz));
      const float d = __fadd_rn(__fadd_rn(__fmul_rn(-2.0f, dt), ss), tt);
      const unsigned mv = monof(d);
      dm[i] = mv;
      const unsigned long long kk = ((unsigned long long)mv << 32) | (unsigned)i;
      const unsigned long long hi = (kk > best) ? kk : best;
      best = (kk < best) ? kk : best;
      sec  = (hi < sec) ? hi : sec;
    }
    gk[g] = best; gk2[g] = sec;
  }
  unsigned dirty = 0;
  // no barrier anywhere: each dm column is written/read only by its own lane
#pragma unroll 1
  for (int k = 0; k < NK; ++k) {
    unsigned long long a0 = gk[0] < gk[1] ? gk[0] : gk[1];
    unsigned long long a1 = gk[2] < gk[3] ? gk[2] : gk[3];
    unsigned long long a2 = gk[4] < gk[5] ? gk[4] : gk[5];
    unsigned long long a3 = gk[6] < gk[7] ? gk[6] : gk[7];
    a0 = a0 < a1 ? a0 : a1;
    a2 = a2 < a3 ? a2 : a3;
    a0 = a0 < a2 ? a0 : a2;
    const unsigned mvl = (unsigned)(a0 >> 32);
    const unsigned bil = (unsigned)a0;
    const unsigned vmin = wave_min_u32(mvl);                   // wave min value
    const unsigned mbi = (mvl == vmin) ? bil : 0xFFFFFFFFu;
    const unsigned widx = wave_min_u32(mbi);                   // smallest idx on tie
    if (L == 0) gidx[(size_t)row*NK + k] = (int)widx;
    const int g = (int)(widx >> 10);                           // uniform group
    const bool owner = ((widx & 63) == (unsigned)L);
    if (owner) {
      dm[widx] = 0xFFFFFFFFu;                                  // clear first
      unsigned long long nbest, nsec;
      if (dirty & (1u << g)) {
        nbest = ~0ull; nsec = ~0ull;                           // rare: rescan
#pragma unroll
        for (int m = 0; m < 16; ++m) {
          const int i2 = L + (g << 10) + (m << 6);
          const unsigned long long kk = ((unsigned long long)dm[i2] << 32) | (unsigned)i2;
          const unsigned long long hi = (kk > nbest) ? kk : nbest;
          nbest = (kk < nbest) ? kk : nbest;
          nsec  = (hi < nsec) ? hi : nsec;
        }
        dirty &= ~(1u << g);
      } else {
        nbest = gk2[g];                                        // true 2nd -> new min
        nsec = ~0ull;
        dirty |= (1u << g);
      }
#pragma unroll
      for (int gg = 0; gg < 8; ++gg) {                         // static writeback
        gk[gg]  = (gg == g) ? nbest : gk[gg];
        gk2[gg] = (gg == g) ? nsec  : gk2[gg];
      }
    }
  }
}

// ---------------------------------------------------------------------------
// Build: F0 in bf16 MFMA-fragment layout F0f[tile][lane][4] (jj<4 slots; k>=9
// are zero) + f32 9-dim first/second moments for layer-0 BN stats.
// ---------------------------------------------------------------------------
__global__ __launch_bounds__(256, 4) void build_kernel(
    const float* __restrict__ xyz, const float* __restrict__ pts,
    const float* __restrict__ newxyz, const int* __restrict__ gidx,
    short* __restrict__ F0f, float* __restrict__ stats0)
{
  float m1[9];
  float m2[45];
#pragma unroll
  for (int a = 0; a < 9; ++a) m1[a] = 0.f;
#pragma unroll
  for (int c = 0; c < 45; ++c) m2[c] = 0.f;
  const int tgid = blockIdx.x * 256 + threadIdx.x;
  for (int it = 0; it < 4; ++it) {
    const int smp = tgid + it * 131072;
    const int row = smp >> 5;
    const int b = row >> 10;
    const int gi = gidx[smp];
    const float* p3 = xyz + ((size_t)b*NPTS + gi)*3;
    const float* p6 = pts + ((size_t)b*NPTS + gi)*6;
    const float* q  = newxyz + (size_t)row*3;
    float f[9];
    f[0] = __fsub_rn(p3[0], q[0]);
    f[1] = __fsub_rn(p3[1], q[1]);
    f[2] = __fsub_rn(p3[2], q[2]);
#pragma unroll
    for (int c = 0; c < 6; ++c) f[3+c] = p6[c];
    const int tile = smp >> 4, col = smp & 15;
    short4* dst = (short4*)F0f;
    short4 s0, s1, s2, s3;
    s0.x = f2bf(f[0]); s0.y = f2bf(f[1]); s0.z = f2bf(f[2]); s0.w = f2bf(f[3]);
    s1.x = f2bf(f[4]); s1.y = f2bf(f[5]); s1.z = f2bf(f[6]); s1.w = f2bf(f[7]);
    s2.x = f2bf(f[8]); s2.y = 0; s2.z = 0; s2.w = 0;
    s3.x = 0; s3.y = 0; s3.z = 0; s3.w = 0;
    dst[(size_t)tile*64 +  0 + col] = s0;
    dst[(size_t)tile*64 + 16 + col] = s1;
    dst[(size_t)tile*64 + 32 + col] = s2;
    dst[(size_t)tile*64 + 48 + col] = s3;
    int cnt = 0;
#pragma unroll
    for (int a = 0; a < 9; ++a) {
      m1[a] += f[a];
#pragma unroll
      for (int b2 = a; b2 < 9; ++b2) { m2[cnt] = fmaf(f[a], f[b2], m2[cnt]); ++cnt; }
    }
  }
#pragma unroll
  for (int off = 32; off >= 1; off >>= 1) {
#pragma unroll
    for (int a = 0; a < 9; ++a) m1[a] += __shfl_xor(m1[a], off);
#pragma unroll
    for (int c = 0; c < 45; ++c) m2[c] += __shfl_xor(m2[c], off);
  }
  __shared__ float sred[4][54];
  const int wid = threadIdx.x >> 6;
  if ((threadIdx.x & 63) == 0) {
#pragma unroll
    for (int a = 0; a < 9; ++a) sred[wid][a] = m1[a];
#pragma unroll
    for (int c = 0; c < 45; ++c) sred[wid][9+c] = m2[c];
  }
  __syncthreads();
  if (threadIdx.x < 54) {
    const float v = sred[0][threadIdx.x] + sred[1][threadIdx.x] +
                    sred[2][threadIdx.x] + sred[3][threadIdx.x];
    atomicAdd(&stats0[threadIdx.x], v);
  }
}

// ---------------------------------------------------------------------------
// Weight fragment tables (bf16, frag layout [frag][lane][8]); run once.
// ---------------------------------------------------------------------------
__global__ void wfrag_prep(const float* __restrict__ w0, const float* __restrict__ w1,
                           const float* __restrict__ w2,
                           short* __restrict__ w0f, short* __restrict__ w1f,
                           short* __restrict__ w2f)
{
  const int t = threadIdx.x;
  for (int it = t; it < 4*64; it += 256) {
    const int Mt = it >> 6, L = it & 63, Q = L >> 4, col = L & 15;
    for (int jj = 0; jj < 8; ++jj) {
      const int k = HK(Q, jj);
      w0f[it*8 + jj] = (k < 9) ? f2bf(w0[(16*Mt + col)*9 + k]) : (short)0;
    }
  }
  for (int it = t; it < 8*64; it += 256) {
    const int fi = it >> 6, L = it & 63, Q = L >> 4, col = L & 15;
    const int Mt = fi >> 1, ks = fi & 1;
    for (int jj = 0; jj < 8; ++jj)
      w1f[it*8 + jj] = f2bf(w1[(16*Mt + col)*64 + 32*ks + HK(Q, jj)]);
  }
  for (int it = t; it < 16*64; it += 256) {
    const int fi = it >> 6, L = it & 63, Q = L >> 4, col = L & 15;
    const int Mt = fi >> 1, ks = fi & 1;
    for (int jj = 0; jj < 8; ++jj)
      w2f[it*8 + jj] = f2bf(w2[(16*Mt + col)*64 + 32*ks + HK(Q, jj)]);
  }
}

// ---------------------------------------------------------------------------
// BN param device helpers (deterministic; recomputed per block).
// ---------------------------------------------------------------------------
__device__ __forceinline__ void bn0_dev(int c, const float* __restrict__ stats0,
    const float* __restrict__ w0, const float* __restrict__ g0,
    const float* __restrict__ bb0, float* __restrict__ sc, float* __restrict__ sf)
{
  const float invn = 1.0f / (float)NSAMP;
  float wv[9];
#pragma unroll
  for (int a = 0; a < 9; ++a) wv[a] = w0[c*9+a];
  float tm = 0.f;
#pragma unroll
  for (int a = 0; a < 9; ++a) tm = fmaf(wv[a], stats0[a], tm);
  float q = 0.f;
  int cnt = 9;
#pragma unroll
  for (int a = 0; a < 9; ++a) {
#pragma unroll
    for (int b2 = a; b2 < 9; ++b2) {
      const float coef = (a == b2) ? (wv[a]*wv[a]) : (2.f*wv[a]*wv[b2]);
      q = fmaf(coef, stats0[cnt], q);
      ++cnt;
    }
  }
  const float mean = tm * invn;
  const float var = q * invn - mean*mean;
  const float scale = g0[c] / sqrtf(var + EPSBN);
  sc[c] = scale;
  sf[c] = fmaf(-mean, scale, bb0[c]);
}

__device__ __forceinline__ void bn_dev(int c, int C, const float* __restrict__ sums,
    const float* __restrict__ g, const float* __restrict__ bb,
    float* __restrict__ sc, float* __restrict__ sf)
{
  const float invn = 1.0f / (float)NSAMP;
  const float mean = sums[c] * invn;
  const float var = sums[C + c] * invn - mean*mean;
  const float scale = g[c] / sqrtf(var + EPSBN);
  sc[c] = scale;
  sf[c] = fmaf(-mean, scale, bb[c]);
}

// ---------------------------------------------------------------------------
// MFMA pass helpers (D layout verified: n=lane&15, m=16*Mt+4*(lane>>4)+reg).
// ---------------------------------------------------------------------------
#define ZERO4 (f32x4){0.f,0.f,0.f,0.f}

__device__ __forceinline__ bf16x8 ldfrag(const short* p, int fi, int L) {
  return ((const bf16x8*)p)[fi*64 + L];
}

__device__ __forceinline__ bf16x8 ldf0(const short* __restrict__ F0f, int tile, int L) {
  const short4 v = ((const short4*)F0f)[(size_t)tile*64 + L];
  bf16x8 b = {0,0,0,0,0,0,0,0};
  b[0] = v.x; b[1] = v.y; b[2] = v.z; b[3] = v.w;
  return b;
}

// ---------------------------------------------------------------------------
// Pass B: GEMM0 -> bn0/relu -> GEMM1 raw; accumulate sum/sumsq per och1.
// ---------------------------------------------------------------------------
__global__ __launch_bounds__(256, 3) void passB_kernel(
    const short* __restrict__ F0f, const short* __restrict__ w0fg,
    const short* __restrict__ w1fg, const float* __restrict__ stats0,
    const float* __restrict__ w0, const float* __restrict__ g0,
    const float* __restrict__ bb0, float* __restrict__ stats1)
{
  __shared__ short lw0[2048];
  __shared__ short lw1[4096];
  __shared__ float lsc0[64], lsf0[64];
  const int tid = threadIdx.x;
  for (int i = tid; i < 256; i += 256) ((int4*)lw0)[i] = ((const int4*)w0fg)[i];
  for (int i = tid; i < 512; i += 256) ((int4*)lw1)[i] = ((const int4*)w1fg)[i];
  if (tid < 64) bn0_dev(tid, stats0, w0, g0, bb0, lsc0, lsf0);
  __syncthreads();
  const int L = tid & 63, Q = L >> 4, wv = tid >> 6;
  float sc0r[4][4], sf0r[4][4];
#pragma unroll
  for (int Mt = 0; Mt < 4; ++Mt)
#pragma unroll
    for (int r = 0; r < 4; ++r) {
      const int och = 16*Mt + 4*Q + r;
      sc0r[Mt][r] = lsc0[och];
      sf0r[Mt][r] = lsf0[och];
    }
  float sS[4][4], sQ2[4][4];
#pragma unroll
  for (int Mt = 0; Mt < 4; ++Mt)
#pragma unroll
    for (int r = 0; r < 4; ++r) { sS[Mt][r] = 0.f; sQ2[Mt][r] = 0.f; }
  const int gw = blockIdx.x*4 + wv;
  for (int t = 0; t < 16; ++t) {
    const int tile = gw*16 + t;
    const bf16x8 b0 = ldf0(F0f, tile, L);
    f32x4 acc0[4];
#pragma unroll
    for (int Mt = 0; Mt < 4; ++Mt)
      acc0[Mt] = __builtin_amdgcn_mfma_f32_16x16x32_bf16(ldfrag(lw0, Mt, L), b0, ZERO4, 0, 0, 0);
    bf16x8 zf[2];
#pragma unroll
    for (int Mt = 0; Mt < 4; ++Mt)
#pragma unroll
      for (int r = 0; r < 4; ++r) {
        const float z = fmaxf(fmaf(acc0[Mt][r], sc0r[Mt][r], sf0r[Mt][r]), 0.f);
        zf[Mt>>1][(Mt&1)*4 + r] = f2bf(z);
      }
    f32x4 acc1[4];
#pragma unroll
    for (int Mt = 0; Mt < 4; ++Mt) {
      acc1[Mt] = __builtin_amdgcn_mfma_f32_16x16x32_bf16(ldfrag(lw1, Mt*2+0, L), zf[0], ZERO4, 0, 0, 0);
      acc1[Mt] = __builtin_amdgcn_mfma_f32_16x16x32_bf16(ldfrag(lw1, Mt*2+1, L), zf[1], acc1[Mt], 0, 0, 0);
    }
#pragma unroll
    for (int Mt = 0; Mt < 4; ++Mt)
#pragma unroll
      for (int r = 0; r < 4; ++r) {
        const float y = acc1[Mt][r];
        sS[Mt][r] += y;
        sQ2[Mt][r] = fmaf(y, y, sQ2[Mt][r]);
      }
  }
#pragma unroll
  for (int Mt = 0; Mt < 4; ++Mt)
#pragma unroll
    for (int r = 0; r < 4; ++r) {
#pragma unroll
      for (int off = 8; off >= 1; off >>= 1) {
        sS[Mt][r]  += __shfl_xor(sS[Mt][r], off);
        sQ2[Mt][r] += __shfl_xor(sQ2[Mt][r], off);
      }
    }
  if ((L & 15) == 0) {
#pragma unroll
    for (int Mt = 0; Mt < 4; ++Mt)
#pragma unroll
      for (int r = 0; r < 4; ++r) {
        const int och = 16*Mt + 4*Q + r;
        atomicAdd(&stats1[och], sS[Mt][r]);
        atomicAdd(&stats1[64+och], sQ2[Mt][r]);
      }
  }
}

// ---------------------------------------------------------------------------
// Pass C: GEMM0 -> GEMM1 -> GEMM2 raw; accumulate sum/sumsq per och2.
// ---------------------------------------------------------------------------
__global__ __launch_bounds__(256, 2) void passC_kernel(
    const short* __restrict__ F0f, const short* __restrict__ w0fg,
    const short* __restrict__ w1fg, const short* __restrict__ w2fg,
    const float* __restrict__ stats0, const float* __restrict__ stats1,
    const float* __restrict__ w0, const float* __restrict__ g0, const float* __restrict__ bb0,
    const float* __restrict__ g1, const float* __restrict__ bb1,
    float* __restrict__ stats2)
{
  __shared__ short lw0[2048];
  __shared__ short lw1[4096];
  __shared__ short lw2[8192];
  __shared__ float lsc0[64], lsf0[64], lsc1[64], lsf1[64];
  const int tid = threadIdx.x;
  for (int i = tid; i < 256; i += 256) ((int4*)lw0)[i] = ((const int4*)w0fg)[i];
  for (int i = tid; i < 512; i += 256) ((int4*)lw1)[i] = ((const int4*)w1fg)[i];
  for (int i = tid; i < 1024; i += 256) ((int4*)lw2)[i] = ((const int4*)w2fg)[i];
  if (tid < 64) bn0_dev(tid, stats0, w0, g0, bb0, lsc0, lsf0);
  else if (tid < 128) bn_dev(tid-64, 64, stats1, g1, bb1, lsc1, lsf1);
  __syncthreads();
  const int L = tid & 63, Q = L >> 4, wv = tid >> 6;
  float sc0r[4][4], sf0r[4][4];
#pragma unroll
  for (int Mt = 0; Mt < 4; ++Mt)
#pragma unroll
    for (int r = 0; r < 4; ++r) {
      const int och = 16*Mt + 4*Q + r;
      sc0r[Mt][r] = lsc0[och];
      sf0r[Mt][r] = lsf0[och];
    }
  float sS[8][4], sQ2[8][4];
#pragma unroll
  for (int Mt = 0; Mt < 8; ++Mt)
#pragma unroll
    for (int r = 0; r < 4; ++r) { sS[Mt][r] = 0.f; sQ2[Mt][r] = 0.f; }
  const int gw = blockIdx.x*4 + wv;
  for (int t = 0; t < 16; ++t) {
    const int tile = gw*16 + t;
    const bf16x8 b0 = ldf0(F0f, tile, L);
    f32x4 acc0[4];
#pragma unroll
    for (int Mt = 0; Mt < 4; ++Mt)
      acc0[Mt] = __builtin_amdgcn_mfma_f32_16x16x32_bf16(ldfrag(lw0, Mt, L), b0, ZERO4, 0, 0, 0);
    bf16x8 zf0[2];
#pragma unroll
    for (int Mt = 0; Mt < 4; ++Mt)
#pragma unroll
      for (int r = 0; r < 4; ++r) {
        const float z = fmaxf(fmaf(acc0[Mt][r], sc0r[Mt][r], sf0r[Mt][r]), 0.f);
        zf0[Mt>>1][(Mt&1)*4 + r] = f2bf(z);
      }
    f32x4 acc1[4];
#pragma unroll
    for (int Mt = 0; Mt < 4; ++Mt) {
      acc1[Mt] = __builtin_amdgcn_mfma_f32_16x16x32_bf16(ldfrag(lw1, Mt*2+0, L), zf0[0], ZERO4, 0, 0, 0);
      acc1[Mt] = __builtin_amdgcn_mfma_f32_16x16x32_bf16(ldfrag(lw1, Mt*2+1, L), zf0[1], acc1[Mt], 0, 0, 0);
    }
    bf16x8 zf1[2];
#pragma unroll
    for (int Mt = 0; Mt < 4; ++Mt)
#pragma unroll
      for (int r = 0; r < 4; ++r) {
        const int och = 16*Mt + 4*Q + r;
        const float z = fmaxf(fmaf(acc1[Mt][r], lsc1[och], lsf1[och]), 0.f);
        zf1[Mt>>1][(Mt&1)*4 + r] = f2bf(z);
      }
#pragma unroll
    for (int Mt = 0; Mt < 8; ++Mt) {
      f32x4 a2;
      a2 = __builtin_amdgcn_mfma_f32_16x16x32_bf16(ldfrag(lw2, Mt*2+0, L), zf1[0], ZERO4, 0, 0, 0);
      a2 = __builtin_amdgcn_mfma_f32_16x16x32_bf16(ldfrag(lw2, Mt*2+1, L), zf1[1], a2, 0, 0, 0);
#pragma unroll
      for (int r = 0; r < 4; ++r) {
        const float y = a2[r];
        sS[Mt][r] += y;
        sQ2[Mt][r] = fmaf(y, y, sQ2[Mt][r]);
      }
    }
  }
#pragma unroll
  for (int Mt = 0; Mt < 8; ++Mt)
#pragma unroll
    for (int r = 0; r < 4; ++r) {
#pragma unroll
      for (int off = 8; off >= 1; off >>= 1) {
        sS[Mt][r]  += __shfl_xor(sS[Mt][r], off);
        sQ2[Mt][r] += __shfl_xor(sQ2[Mt][r], off);
      }
    }
  if ((L & 15) == 0) {
#pragma unroll
    for (int Mt = 0; Mt < 8; ++Mt)
#pragma unroll
      for (int r = 0; r < 4; ++r) {
        const int och = 16*Mt + 4*Q + r;
        atomicAdd(&stats2[och], sS[Mt][r]);
        atomicAdd(&stats2[128+och], sQ2[Mt][r]);
      }
  }
}

// ---------------------------------------------------------------------------
// Pass D: full pipeline + bn2/relu + maxpool over 32 samples -> new_points.
// ---------------------------------------------------------------------------
__global__ __launch_bounds__(256, 2) void passD_kernel(
    const short* __restrict__ F0f, const short* __restrict__ w0fg,
    const short* __restrict__ w1fg, const short* __restrict__ w2fg,
    const float* __restrict__ stats0, const float* __restrict__ stats1,
    const float* __restrict__ stats2,
    const float* __restrict__ w0, const float* __restrict__ g0, const float* __restrict__ bb0,
    const float* __restrict__ g1, const float* __restrict__ bb1,
    const float* __restrict__ g2, const float* __restrict__ bb2,
    float* __restrict__ outnp)
{
  __shared__ short lw0[2048];
  __shared__ short lw1[4096];
  __shared__ short lw2[8192];
  __shared__ float lsc0[64], lsf0[64], lsc1[64], lsf1[64], lsc2[128], lsf2[128];
  const int tid = threadIdx.x;
  for (int i = tid; i < 256; i += 256) ((int4*)lw0)[i] = ((const int4*)w0fg)[i];
  for (int i = tid; i < 512; i += 256) ((int4*)lw1)[i] = ((const int4*)w1fg)[i];
  for (int i = tid; i < 1024; i += 256) ((int4*)lw2)[i] = ((const int4*)w2fg)[i];
  if (tid < 64) bn0_dev(tid, stats0, w0, g0, bb0, lsc0, lsf0);
  else if (tid < 128) bn_dev(tid-64, 64, stats1, g1, bb1, lsc1, lsf1);
  else bn_dev(tid-128, 128, stats2, g2, bb2, lsc2, lsf2);
  __syncthreads();
  const int L = tid & 63, Q = L >> 4, wv = tid >> 6;
  float sc0r[4][4], sf0r[4][4];
#pragma unroll
  for (int Mt = 0; Mt < 4; ++Mt)
#pragma unroll
    for (int r = 0; r < 4; ++r) {
      const int och = 16*Mt + 4*Q + r;
      sc0r[Mt][r] = lsc0[och];
      sf0r[Mt][r] = lsf0[och];
    }
  float m2a[8][4];
#pragma unroll
  for (int Mt = 0; Mt < 8; ++Mt)
#pragma unroll
    for (int r = 0; r < 4; ++r) m2a[Mt][r] = 0.f;
  const int gw = blockIdx.x*4 + wv;
  for (int t = 0; t < 16; ++t) {
    const int tile = gw*16 + t;
    const bf16x8 b0 = ldf0(F0f, tile, L);
    f32x4 acc0[4];
#pragma unroll
    for (int Mt = 0; Mt < 4; ++Mt)
      acc0[Mt] = __builtin_amdgcn_mfma_f32_16x16x32_bf16(ldfrag(lw0, Mt, L), b0, ZERO4, 0, 0, 0);
    bf16x8 zf0[2];
#pragma unroll
    for (int Mt = 0; Mt < 4; ++Mt)
#pragma unroll
      for (int r = 0; r < 4; ++r) {
        const float z = fmaxf(fmaf(acc0[Mt][r], sc0r[Mt][r], sf0r[Mt][r]), 0.f);
        zf0[Mt>>1][(Mt&1)*4 + r] = f2bf(z);
      }
    f32x4 acc1[4];
#pragma unroll
    for (int Mt = 0; Mt < 4; ++Mt) {
      acc1[Mt] = __builtin_amdgcn_mfma_f32_16x16x32_bf16(ldfrag(lw1, Mt*2+0, L), zf0[0], ZERO4, 0, 0, 0);
      acc1[Mt] = __builtin_amdgcn_mfma_f32_16x16x32_bf16(ldfrag(lw1, Mt*2+1, L), zf0[1], acc1[Mt], 0, 0, 0);
    }
    bf16x8 zf1[2];
#pragma unroll
    for (int Mt = 0; Mt < 4; ++Mt)
#pragma unroll
      for (int r = 0; r < 4; ++r) {
        const int och = 16*Mt + 4*Q + r;
        const float z = fmaxf(fmaf(acc1[Mt][r], lsc1[och], lsf1[och]), 0.f);
        zf1[Mt>>1][(Mt&1)*4 + r] = f2bf(z);
      }
#pragma unroll
    for (int Mt = 0; Mt < 8; ++Mt) {
      f32x4 a2;
      a2 = __builtin_amdgcn_mfma_f32_16x16x32_bf16(ldfrag(lw2, Mt*2+0, L), zf1[0], ZERO4, 0, 0, 0);
      a2 = __builtin_amdgcn_mfma_f32_16x16x32_bf16(ldfrag(lw2, Mt*2+1, L), zf1[1], a2, 0, 0, 0);
#pragma unroll
      for (int r = 0; r < 4; ++r) {
        const int och = 16*Mt + 4*Q + r;
        const float z2 = fmaxf(fmaf(a2[r], lsc2[och], lsf2[och]), 0.f);
        m2a[Mt][r] = fmaxf(m2a[Mt][r], z2);
      }
    }
    if (t & 1) {   // completed a row of 32 samples
#pragma unroll
      for (int Mt = 0; Mt < 8; ++Mt)
#pragma unroll
        for (int r = 0; r < 4; ++r) {
          float v = m2a[Mt][r];
#pragma unroll
          for (int off = 8; off >= 1; off >>= 1) v = fmaxf(v, __shfl_xor(v, off));
          m2a[Mt][r] = v;
        }
      if ((L & 15) == 0) {
        const size_t row = tile >> 1;
#pragma unroll
        for (int Mt = 0; Mt < 8; ++Mt) {
          float4 o;
          o.x = m2a[Mt][0]; o.y = m2a[Mt][1]; o.z = m2a[Mt][2]; o.w = m2a[Mt][3];
          *(float4*)&outnp[row*128 + 16*Mt + 4*Q] = o;
        }
      }
#pragma unroll
      for (int Mt = 0; Mt < 8; ++Mt)
#pragma unroll
        for (int r = 0; r < 4; ++r) m2a[Mt][r] = 0.f;
    }
  }
}

// ---------------------------------------------------------------------------
extern "C" void kernel_launch(void* const* d_in, const int* in_sizes, int n_in,
                              void* d_out, int out_size, void* d_ws, size_t ws_size,
                              hipStream_t stream)
{
  const float* xyz = (const float*)d_in[0];
  const float* pts = (const float*)d_in[1];
  const float* w0  = (const float*)d_in[2];
  const float* g0  = (const float*)d_in[4];
  const float* bb0 = (const float*)d_in[5];
  const float* w1  = (const float*)d_in[6];
  const float* g1  = (const float*)d_in[8];
  const float* bb1 = (const float*)d_in[9];
  const float* w2  = (const float*)d_in[10];
  const float* g2  = (const float*)d_in[12];
  const float* bb2 = (const float*)d_in[13];

  float* out    = (float*)d_out;
  float* newxyz = out;                     // [16,1024,3]
  float* outnp  = out + (size_t)NB*NS*3;   // [16,1024,128]

  char* ws = (char*)d_ws;
  int*   gidx = (int*)(ws);                                  // 2 MB
  short* F0f  = (short*)(ws + 2097152);                      // 16.78 MB (bf16 frags)
  char*  p    = ws + 2097152 + 16777216;
  short* w0f  = (short*)(p);            // 4096 B
  short* w1f  = (short*)(p + 4096);     // 8192 B
  short* w2f  = (short*)(p + 12288);    // 16384 B
  float* stats  = (float*)(p + 28672);
  float* stats0 = stats;              // 64 (54 used)
  float* stats1 = stats + 64;         // 128
  float* stats2 = stats + 64 + 128;   // 256
  float* pp     = (float*)(p + 28672 + 2048);  // 16x8192 f32 = 512 KB
  const size_t needed = 2097152 + 16777216 + 28672 + 2048 + (size_t)NB*NPTS*4;
  if (ws_size < needed) return;

  hipMemsetAsync(stats, 0, 448 * sizeof(float), stream);
  wfrag_prep  <<<1,     256,  0, stream>>>(w0, w1, w2, w0f, w1f, w2f);
  fps_kernel  <<<NB,    512,  0, stream>>>(xyz, newxyz, pp);
  knn_kernel  <<<16384, 64,   0, stream>>>(xyz, pp, newxyz, gidx);
  build_kernel<<<512,   256,  0, stream>>>(xyz, pts, newxyz, gidx, F0f, stats0);
  passB_kernel<<<512,   256,  0, stream>>>(F0f, w0f, w1f, stats0, w0, g0, bb0, stats1);
  passC_kernel<<<512,   256,  0, stream>>>(F0f, w0f, w1f, w2f, stats0, stats1,
                                           w0, g0, bb0, g1, bb1, stats2);
  passD_kernel<<<512,   256,  0, stream>>>(F0f, w0f, w1f, w2f, stats0, stats1, stats2,
                                           w0, g0, bb0, g1, bb1, g2, bb2, outnp);
}

// Round 15
// 1591.315 us; speedup vs baseline: 1.2398x; 1.2398x over previous
//
#include <hip/hip_runtime.h>
#include <hip/hip_bf16.h>

#define NPTS 8192
#define NB 16
#define NS 1024
#define NK 32
#define NSAMP (NB*NS*NK)  // 524288
#define NTILE (NSAMP/16)  // 32768 sample-tiles of 16
#define EPSBN 1e-5f

// Chosen k-mapping for MFMA fragments (any consistent bijection works:
// it cancels between A and B; chosen so the D->B bridge is lane-local).
#define HK(Q, JJ) (4*(Q) + ((JJ)&3) + 16*((JJ)>>2))

typedef __attribute__((ext_vector_type(8))) short bf16x8;
typedef __attribute__((ext_vector_type(4))) float f32x4;

__device__ __forceinline__ short f2bf(float x) {
  union { __hip_bfloat16 h; short s; } u;
  u.h = __float2bfloat16(x);
  return u.s;
}

// monotone float->uint mapping (preserves order for min/max on unsigned).
// REQUIRED for kNN keys: self-distance rounds to tiny NEGATIVE floats; raw
// float bits as unsigned would sort them last (R6 bug). Finite/NaN inputs
// map <= 0xFFC00000 < 0xFFFFFFFF, so ~0ull is a safe sentinel key.
__device__ __forceinline__ unsigned monof(float f) {
  unsigned u = __float_as_uint(f);
  return u ^ ((unsigned)((int)u >> 31) | 0x80000000u);
}

// ---------------------------------------------------------------------------
// Wave64 SINGLE-VALUE reductions via DPP. Each step fuses to ONE VALU op
// (v_max/min_u32 with DPP source modifier) — R12's paired (value,index)
// chain could NOT fuse (5 ops/step) and REGRESSED; do not reintroduce.
// Argmax/argmin = value chain, then masked-index min chain (exact
// smallest-index tie-break). Sequence: row_shr 1/2/4/8, row_bcast:15,
// row_bcast:31; lane 63 holds the result; readlane broadcasts.
// ---------------------------------------------------------------------------
__device__ __forceinline__ unsigned wave_max_u32(unsigned v) {
  unsigned t;
  t = (unsigned)__builtin_amdgcn_update_dpp(0, (int)v, 0x111, 0xf, 0xf, false); v = v > t ? v : t;
  t = (unsigned)__builtin_amdgcn_update_dpp(0, (int)v, 0x112, 0xf, 0xf, false); v = v > t ? v : t;
  t = (unsigned)__builtin_amdgcn_update_dpp(0, (int)v, 0x114, 0xf, 0xf, false); v = v > t ? v : t;
  t = (unsigned)__builtin_amdgcn_update_dpp(0, (int)v, 0x118, 0xf, 0xf, false); v = v > t ? v : t;
  t = (unsigned)__builtin_amdgcn_update_dpp(0, (int)v, 0x142, 0xa, 0xf, false); v = v > t ? v : t;
  t = (unsigned)__builtin_amdgcn_update_dpp(0, (int)v, 0x143, 0xc, 0xf, false); v = v > t ? v : t;
  return (unsigned)__builtin_amdgcn_readlane((int)v, 63);
}

__device__ __forceinline__ unsigned wave_min_u32(unsigned v) {
  unsigned t;
  t = (unsigned)__builtin_amdgcn_update_dpp(-1, (int)v, 0x111, 0xf, 0xf, false); v = v < t ? v : t;
  t = (unsigned)__builtin_amdgcn_update_dpp(-1, (int)v, 0x112, 0xf, 0xf, false); v = v < t ? v : t;
  t = (unsigned)__builtin_amdgcn_update_dpp(-1, (int)v, 0x114, 0xf, 0xf, false); v = v < t ? v : t;
  t = (unsigned)__builtin_amdgcn_update_dpp(-1, (int)v, 0x118, 0xf, 0xf, false); v = v < t ? v : t;
  t = (unsigned)__builtin_amdgcn_update_dpp(-1, (int)v, 0x142, 0xa, 0xf, false); v = v < t ? v : t;
  t = (unsigned)__builtin_amdgcn_update_dpp(-1, (int)v, 0x143, 0xc, 0xf, false); v = v < t ? v : t;
  return (unsigned)__builtin_amdgcn_readlane((int)v, 63);
}

// ---------------------------------------------------------------------------
// FPS (R13 exact — structural floor 855us after R9/R14 multi-wave attempts
// both regressed): 1 block/batch, 256 thr (1 wave/SIMD), xyz in LDS, LDS
// centroid accum + one flush, pp epilogue; DPP value chain + masked-index
// chain. Selection math/rounding: no-FMA, monof, smallest-idx ties.
// ---------------------------------------------------------------------------
__global__ __launch_bounds__(256, 1) void fps_kernel(
    const float* __restrict__ xyz, float* __restrict__ newxyz, float* __restrict__ pp)
{
  __shared__ float sx[NPTS*3];                 // 96 KB
  __shared__ float cs[NS*3];                   // 12 KB centroid accum
  __shared__ unsigned long long kred[2][4];
  const int b = blockIdx.x, tid = threadIdx.x;
  const float* xb = xyz + (size_t)b * NPTS * 3;
  for (int i = tid; i < NPTS*3; i += 256) sx[i] = xb[i];
  __syncthreads();
  float px[32], py[32], pz[32], dist[32];
#pragma unroll
  for (int j = 0; j < 32; ++j) {
    const int i = tid + j*256;
    px[j] = sx[3*i]; py[j] = sx[3*i+1]; pz[j] = sx[3*i+2];
    dist[j] = 1e10f;
  }
  const int wid = tid >> 6;
  int far = 0;
  for (int t = 0; t < NS; ++t) {
    const float cx = sx[3*far], cy = sx[3*far+1], cz = sx[3*far+2];
    if (tid == 0) { cs[t*3] = cx; cs[t*3+1] = cy; cs[t*3+2] = cz; }
    float bv = -1.0f; int bj = 0;
#pragma unroll
    for (int j = 0; j < 32; ++j) {
      const float dx = __fsub_rn(px[j], cx);
      const float dy = __fsub_rn(py[j], cy);
      const float dz = __fsub_rn(pz[j], cz);
      const float d = __fadd_rn(__fadd_rn(__fmul_rn(dx,dx), __fmul_rn(dy,dy)), __fmul_rn(dz,dz));
      const float dj = fminf(dist[j], d);
      dist[j] = dj;
      const bool m = dj > bv;          // j ascending -> keeps smallest idx on tie
      bv = m ? dj : bv;
      bj = m ? j : bj;
    }
    const unsigned bi = (unsigned)(tid + bj*256);
    const unsigned mv = monof(bv);
    const unsigned vmax = wave_max_u32(mv);                    // wave max value
    const unsigned mbi = (mv == vmax) ? bi : 0xFFFFFFFFu;
    const unsigned bimin = wave_min_u32(mbi);                  // smallest idx on tie
    if ((tid & 63) == 0)
      kred[t & 1][wid] = ((unsigned long long)vmax << 32) | (unsigned)(8191 - bimin);
    __syncthreads();
    unsigned long long k0 = kred[t & 1][0], k1 = kred[t & 1][1];
    unsigned long long k2 = kred[t & 1][2], k3 = kred[t & 1][3];
    k0 = (k1 > k0) ? k1 : k0;
    k2 = (k3 > k2) ? k3 : k2;
    k0 = (k2 > k0) ? k2 : k0;           // max; tie -> larger (8191-idx) = smaller idx
    far = 8191 - (int)(k0 & 0xffffffffu);
  }
  // flush centroids (coalesced) and |p|^2 epilogue (knn's exact tt rounding)
  __syncthreads();
  float* nb = newxyz + (size_t)b * NS * 3;
  for (int idx = tid; idx < NS*3; idx += 256) nb[idx] = cs[idx];
  float* ppb = pp + (size_t)b * NPTS;
#pragma unroll
  for (int j = 0; j < 32; ++j) {
    const int i = tid + j*256;
    ppb[i] = __fadd_rn(__fadd_rn(__fmul_rn(px[j],px[j]), __fmul_rn(py[j],py[j])), __fmul_rn(pz[j],pz[j]));
  }
}

// sorted insert of kk into ascending (a,b,c) triple, branch-free
#define INS3(kk, a, b, c) { \
    const bool lA = (kk) < (a), lB = (kk) < (b), lC = (kk) < (c); \
    const unsigned long long na = lA ? (kk) : (a); \
    const unsigned long long nb = lA ? (a) : (lB ? (kk) : (b)); \
    const unsigned long long nc = lB ? (b) : (lC ? (kk) : (c)); \
    (a) = na; (b) = nb; (c) = nc; }

// ---------------------------------------------------------------------------
// kNN v5: ONE WAVE per query, ZERO LDS, ZERO barriers. Register-resident
// 3-deep tournament. Lane L owns i = L + 64m; 8 groups of 16
// (i = L + 1024g + 64m). Fill: per-group ascending stack (k1,k2,k3) of
// packed keys (monof(d)<<32)|i (distinct idx -> exact order & ties).
// Per round: 3-level tree min over k1[8] -> DPP value-min chain ->
// masked-index min chain -> widx (exact smallest-index tie-break).
// The popped element is ALWAYS the owner lane's k1[g] (global min is some
// group's stack top, and stack tops are true group minima by induction):
// owner marks consumed bit, promotes (k2,k3); if the promoted top is the
// sentinel (3rd pop since refill, ~2% of rounds), recompute the group's
// keys from global (L2-hot) with consumed entries masked to sentinel.
// Sentinel ~0ull loses to every real key (monof <= 0xFFC00000).
// 0 LDS -> occupancy limited only by ~100 VGPRs (~3x the old 5 waves/CU).
// Exactly reproduces lax.top_k(-d) order incl. smallest-index tie-break.
// ---------------------------------------------------------------------------
__global__ __launch_bounds__(64) void knn_kernel(
    const float* __restrict__ xyz, const float* __restrict__ pp,
    const float* __restrict__ newxyz, int* __restrict__ gidx)
{
  const int L = threadIdx.x;
  const int row = blockIdx.x;
  const int b = row >> 10;
  const float* xb = xyz + (size_t)b * NPTS * 3;
  const float* ppb = pp + (size_t)b * NPTS;
  const float qx = newxyz[(size_t)row*3+0];
  const float qy = newxyz[(size_t)row*3+1];
  const float qz = newxyz[(size_t)row*3+2];
  const float ss = __fadd_rn(__fadd_rn(__fmul_rn(qx,qx), __fmul_rn(qy,qy)), __fmul_rn(qz,qz));
  unsigned long long k1[8], k2[8], k3[8];
#pragma unroll
  for (int g = 0; g < 8; ++g) {
    unsigned long long a = ~0ull, bb = ~0ull, c = ~0ull;
#pragma unroll
    for (int m = 0; m < 16; ++m) {
      const int i = L + (g << 10) + (m << 6);
      const float tx = xb[3*i], ty = xb[3*i+1], tz = xb[3*i+2];
      const float tt = ppb[i];     // same bits as inline (x^2+y^2)+z^2
      const float dt = __fadd_rn(__fadd_rn(__fmul_rn(qx,tx), __fmul_rn(qy,ty)), __fmul_rn(qz,tz));
      const float d = __fadd_rn(__fadd_rn(__fmul_rn(-2.0f, dt), ss), tt);
      const unsigned long long kk = ((unsigned long long)monof(d) << 32) | (unsigned)i;
      INS3(kk, a, bb, c)
    }
    k1[g] = a; k2[g] = bb; k3[g] = c;
  }
  unsigned long long cm0 = 0, cm1 = 0;   // consumed bits: 16 per group
#pragma unroll 1
  for (int k = 0; k < NK; ++k) {
    unsigned long long a0 = k1[0] < k1[1] ? k1[0] : k1[1];
    unsigned long long a1 = k1[2] < k1[3] ? k1[2] : k1[3];
    unsigned long long a2 = k1[4] < k1[5] ? k1[4] : k1[5];
    unsigned long long a3 = k1[6] < k1[7] ? k1[6] : k1[7];
    a0 = a0 < a1 ? a0 : a1;
    a2 = a2 < a3 ? a2 : a3;
    a0 = a0 < a2 ? a0 : a2;
    const unsigned mvl = (unsigned)(a0 >> 32);
    const unsigned bil = (unsigned)a0;
    const unsigned vmin = wave_min_u32(mvl);                   // wave min value
    const unsigned mbi = (mvl == vmin) ? bil : 0xFFFFFFFFu;
    const unsigned widx = wave_min_u32(mbi);                   // smallest idx on tie
    if (L == 0) gidx[(size_t)row*NK + k] = (int)widx;
    const int g = (int)(widx >> 10);
    const int m = (int)((widx >> 6) & 15);
    const bool owner = ((widx & 63) == (unsigned)L);
    if (owner) {
      const unsigned long long bit = 1ull << (((g & 3) << 4) + m);
      if (g < 4) cm0 |= bit; else cm1 |= bit;
      // extract (k2,k3) of group g via static selects
      unsigned long long s2 = k2[0], s3 = k3[0];
#pragma unroll
      for (int gg = 1; gg < 8; ++gg) {
        s2 = (gg == g) ? k2[gg] : s2;
        s3 = (gg == g) ? k3[gg] : s3;
      }
      unsigned long long n1 = s2, n2 = s3, n3 = ~0ull;
      if (n1 == ~0ull) {                                       // rare: refill
        const unsigned msk = (unsigned)(((g < 4) ? cm0 : cm1) >> ((g & 3) << 4)) & 0xFFFFu;
        n1 = ~0ull; n2 = ~0ull; n3 = ~0ull;
#pragma unroll
        for (int m2 = 0; m2 < 16; ++m2) {
          const int i2 = L + (g << 10) + (m2 << 6);
          const float tx = xb[3*i2], ty = xb[3*i2+1], tz = xb[3*i2+2];
          const float tt = ppb[i2];
          const float dt = __fadd_rn(__fadd_rn(__fmul_rn(qx,tx), __fmul_rn(qy,ty)), __fmul_rn(qz,tz));
          const float d = __fadd_rn(__fadd_rn(__fmul_rn(-2.0f, dt), ss), tt);
          unsigned long long kk = ((unsigned long long)monof(d) << 32) | (unsigned)i2;
          kk = ((msk >> m2) & 1u) ? ~0ull : kk;                // consumed -> sentinel
          INS3(kk, n1, n2, n3)
        }
      }
#pragma unroll
      for (int gg = 0; gg < 8; ++gg) {                         // static writeback
        k1[gg] = (gg == g) ? n1 : k1[gg];
        k2[gg] = (gg == g) ? n2 : k2[gg];
        k3[gg] = (gg == g) ? n3 : k3[gg];
      }
    }
  }
}

// ---------------------------------------------------------------------------
// Build: F0 in bf16 MFMA-fragment layout F0f[tile][lane][4] (jj<4 slots; k>=9
// are zero) + f32 9-dim first/second moments for layer-0 BN stats.
// ---------------------------------------------------------------------------
__global__ __launch_bounds__(256, 4) void build_kernel(
    const float* __restrict__ xyz, const float* __restrict__ pts,
    const float* __restrict__ newxyz, const int* __restrict__ gidx,
    short* __restrict__ F0f, float* __restrict__ stats0)
{
  float m1[9];
  float m2[45];
#pragma unroll
  for (int a = 0; a < 9; ++a) m1[a] = 0.f;
#pragma unroll
  for (int c = 0; c < 45; ++c) m2[c] = 0.f;
  const int tgid = blockIdx.x * 256 + threadIdx.x;
  for (int it = 0; it < 4; ++it) {
    const int smp = tgid + it * 131072;
    const int row = smp >> 5;
    const int b = row >> 10;
    const int gi = gidx[smp];
    const float* p3 = xyz + ((size_t)b*NPTS + gi)*3;
    const float* p6 = pts + ((size_t)b*NPTS + gi)*6;
    const float* q  = newxyz + (size_t)row*3;
    float f[9];
    f[0] = __fsub_rn(p3[0], q[0]);
    f[1] = __fsub_rn(p3[1], q[1]);
    f[2] = __fsub_rn(p3[2], q[2]);
#pragma unroll
    for (int c = 0; c < 6; ++c) f[3+c] = p6[c];
    const int tile = smp >> 4, col = smp & 15;
    short4* dst = (short4*)F0f;
    short4 s0, s1, s2, s3;
    s0.x = f2bf(f[0]); s0.y = f2bf(f[1]); s0.z = f2bf(f[2]); s0.w = f2bf(f[3]);
    s1.x = f2bf(f[4]); s1.y = f2bf(f[5]); s1.z = f2bf(f[6]); s1.w = f2bf(f[7]);
    s2.x = f2bf(f[8]); s2.y = 0; s2.z = 0; s2.w = 0;
    s3.x = 0; s3.y = 0; s3.z = 0; s3.w = 0;
    dst[(size_t)tile*64 +  0 + col] = s0;
    dst[(size_t)tile*64 + 16 + col] = s1;
    dst[(size_t)tile*64 + 32 + col] = s2;
    dst[(size_t)tile*64 + 48 + col] = s3;
    int cnt = 0;
#pragma unroll
    for (int a = 0; a < 9; ++a) {
      m1[a] += f[a];
#pragma unroll
      for (int b2 = a; b2 < 9; ++b2) { m2[cnt] = fmaf(f[a], f[b2], m2[cnt]); ++cnt; }
    }
  }
#pragma unroll
  for (int off = 32; off >= 1; off >>= 1) {
#pragma unroll
    for (int a = 0; a < 9; ++a) m1[a] += __shfl_xor(m1[a], off);
#pragma unroll
    for (int c = 0; c < 45; ++c) m2[c] += __shfl_xor(m2[c], off);
  }
  __shared__ float sred[4][54];
  const int wid = threadIdx.x >> 6;
  if ((threadIdx.x & 63) == 0) {
#pragma unroll
    for (int a = 0; a < 9; ++a) sred[wid][a] = m1[a];
#pragma unroll
    for (int c = 0; c < 45; ++c) sred[wid][9+c] = m2[c];
  }
  __syncthreads();
  if (threadIdx.x < 54) {
    const float v = sred[0][threadIdx.x] + sred[1][threadIdx.x] +
                    sred[2][threadIdx.x] + sred[3][threadIdx.x];
    atomicAdd(&stats0[threadIdx.x], v);
  }
}

// ---------------------------------------------------------------------------
// Weight fragment tables (bf16, frag layout [frag][lane][8]); run once.
// ---------------------------------------------------------------------------
__global__ void wfrag_prep(const float* __restrict__ w0, const float* __restrict__ w1,
                           const float* __restrict__ w2,
                           short* __restrict__ w0f, short* __restrict__ w1f,
                           short* __restrict__ w2f)
{
  const int t = threadIdx.x;
  for (int it = t; it < 4*64; it += 256) {
    const int Mt = it >> 6, L = it & 63, Q = L >> 4, col = L & 15;
    for (int jj = 0; jj < 8; ++jj) {
      const int k = HK(Q, jj);
      w0f[it*8 + jj] = (k < 9) ? f2bf(w0[(16*Mt + col)*9 + k]) : (short)0;
    }
  }
  for (int it = t; it < 8*64; it += 256) {
    const int fi = it >> 6, L = it & 63, Q = L >> 4, col = L & 15;
    const int Mt = fi >> 1, ks = fi & 1;
    for (int jj = 0; jj < 8; ++jj)
      w1f[it*8 + jj] = f2bf(w1[(16*Mt + col)*64 + 32*ks + HK(Q, jj)]);
  }
  for (int it = t; it < 16*64; it += 256) {
    const int fi = it >> 6, L = it & 63, Q = L >> 4, col = L & 15;
    const int Mt = fi >> 1, ks = fi & 1;
    for (int jj = 0; jj < 8; ++jj)
      w2f[it*8 + jj] = f2bf(w2[(16*Mt + col)*64 + 32*ks + HK(Q, jj)]);
  }
}

// ---------------------------------------------------------------------------
// BN param device helpers (deterministic; recomputed per block).
// ---------------------------------------------------------------------------
__device__ __forceinline__ void bn0_dev(int c, const float* __restrict__ stats0,
    const float* __restrict__ w0, const float* __restrict__ g0,
    const float* __restrict__ bb0, float* __restrict__ sc, float* __restrict__ sf)
{
  const float invn = 1.0f / (float)NSAMP;
  float wv[9];
#pragma unroll
  for (int a = 0; a < 9; ++a) wv[a] = w0[c*9+a];
  float tm = 0.f;
#pragma unroll
  for (int a = 0; a < 9; ++a) tm = fmaf(wv[a], stats0[a], tm);
  float q = 0.f;
  int cnt = 9;
#pragma unroll
  for (int a = 0; a < 9; ++a) {
#pragma unroll
    for (int b2 = a; b2 < 9; ++b2) {
      const float coef = (a == b2) ? (wv[a]*wv[a]) : (2.f*wv[a]*wv[b2]);
      q = fmaf(coef, stats0[cnt], q);
      ++cnt;
    }
  }
  const float mean = tm * invn;
  const float var = q * invn - mean*mean;
  const float scale = g0[c] / sqrtf(var + EPSBN);
  sc[c] = scale;
  sf[c] = fmaf(-mean, scale, bb0[c]);
}

__device__ __forceinline__ void bn_dev(int c, int C, const float* __restrict__ sums,
    const float* __restrict__ g, const float* __restrict__ bb,
    float* __restrict__ sc, float* __restrict__ sf)
{
  const float invn = 1.0f / (float)NSAMP;
  const float mean = sums[c] * invn;
  const float var = sums[C + c] * invn - mean*mean;
  const float scale = g[c] / sqrtf(var + EPSBN);
  sc[c] = scale;
  sf[c] = fmaf(-mean, scale, bb[c]);
}

// ---------------------------------------------------------------------------
// MFMA pass helpers (D layout verified: n=lane&15, m=16*Mt+4*(lane>>4)+reg).
// ---------------------------------------------------------------------------
#define ZERO4 (f32x4){0.f,0.f,0.f,0.f}

__device__ __forceinline__ bf16x8 ldfrag(const short* p, int fi, int L) {
  return ((const bf16x8*)p)[fi*64 + L];
}

__device__ __forceinline__ bf16x8 ldf0(const short* __restrict__ F0f, int tile, int L) {
  const short4 v = ((const short4*)F0f)[(size_t)tile*64 + L];
  bf16x8 b = {0,0,0,0,0,0,0,0};
  b[0] = v.x; b[1] = v.y; b[2] = v.z; b[3] = v.w;
  return b;
}

// ---------------------------------------------------------------------------
// Pass B: GEMM0 -> bn0/relu -> GEMM1 raw; accumulate sum/sumsq per och1.
// ---------------------------------------------------------------------------
__global__ __launch_bounds__(256, 3) void passB_kernel(
    const short* __restrict__ F0f, const short* __restrict__ w0fg,
    const short* __restrict__ w1fg, const float* __restrict__ stats0,
    const float* __restrict__ w0, const float* __restrict__ g0,
    const float* __restrict__ bb0, float* __restrict__ stats1)
{
  __shared__ short lw0[2048];
  __shared__ short lw1[4096];
  __shared__ float lsc0[64], lsf0[64];
  const int tid = threadIdx.x;
  for (int i = tid; i < 256; i += 256) ((int4*)lw0)[i] = ((const int4*)w0fg)[i];
  for (int i = tid; i < 512; i += 256) ((int4*)lw1)[i] = ((const int4*)w1fg)[i];
  if (tid < 64) bn0_dev(tid, stats0, w0, g0, bb0, lsc0, lsf0);
  __syncthreads();
  const int L = tid & 63, Q = L >> 4, wv = tid >> 6;
  float sc0r[4][4], sf0r[4][4];
#pragma unroll
  for (int Mt = 0; Mt < 4; ++Mt)
#pragma unroll
    for (int r = 0; r < 4; ++r) {
      const int och = 16*Mt + 4*Q + r;
      sc0r[Mt][r] = lsc0[och];
      sf0r[Mt][r] = lsf0[och];
    }
  float sS[4][4], sQ2[4][4];
#pragma unroll
  for (int Mt = 0; Mt < 4; ++Mt)
#pragma unroll
    for (int r = 0; r < 4; ++r) { sS[Mt][r] = 0.f; sQ2[Mt][r] = 0.f; }
  const int gw = blockIdx.x*4 + wv;
  for (int t = 0; t < 16; ++t) {
    const int tile = gw*16 + t;
    const bf16x8 b0 = ldf0(F0f, tile, L);
    f32x4 acc0[4];
#pragma unroll
    for (int Mt = 0; Mt < 4; ++Mt)
      acc0[Mt] = __builtin_amdgcn_mfma_f32_16x16x32_bf16(ldfrag(lw0, Mt, L), b0, ZERO4, 0, 0, 0);
    bf16x8 zf[2];
#pragma unroll
    for (int Mt = 0; Mt < 4; ++Mt)
#pragma unroll
      for (int r = 0; r < 4; ++r) {
        const float z = fmaxf(fmaf(acc0[Mt][r], sc0r[Mt][r], sf0r[Mt][r]), 0.f);
        zf[Mt>>1][(Mt&1)*4 + r] = f2bf(z);
      }
    f32x4 acc1[4];
#pragma unroll
    for (int Mt = 0; Mt < 4; ++Mt) {
      acc1[Mt] = __builtin_amdgcn_mfma_f32_16x16x32_bf16(ldfrag(lw1, Mt*2+0, L), zf[0], ZERO4, 0, 0, 0);
      acc1[Mt] = __builtin_amdgcn_mfma_f32_16x16x32_bf16(ldfrag(lw1, Mt*2+1, L), zf[1], acc1[Mt], 0, 0, 0);
    }
#pragma unroll
    for (int Mt = 0; Mt < 4; ++Mt)
#pragma unroll
      for (int r = 0; r < 4; ++r) {
        const float y = acc1[Mt][r];
        sS[Mt][r] += y;
        sQ2[Mt][r] = fmaf(y, y, sQ2[Mt][r]);
      }
  }
#pragma unroll
  for (int Mt = 0; Mt < 4; ++Mt)
#pragma unroll
    for (int r = 0; r < 4; ++r) {
#pragma unroll
      for (int off = 8; off >= 1; off >>= 1) {
        sS[Mt][r]  += __shfl_xor(sS[Mt][r], off);
        sQ2[Mt][r] += __shfl_xor(sQ2[Mt][r], off);
      }
    }
  if ((L & 15) == 0) {
#pragma unroll
    for (int Mt = 0; Mt < 4; ++Mt)
#pragma unroll
      for (int r = 0; r < 4; ++r) {
        const int och = 16*Mt + 4*Q + r;
        atomicAdd(&stats1[och], sS[Mt][r]);
        atomicAdd(&stats1[64+och], sQ2[Mt][r]);
      }
  }
}

// ---------------------------------------------------------------------------
// Pass C: GEMM0 -> GEMM1 -> GEMM2 raw; accumulate sum/sumsq per och2.
// ---------------------------------------------------------------------------
__global__ __launch_bounds__(256, 2) void passC_kernel(
    const short* __restrict__ F0f, const short* __restrict__ w0fg,
    const short* __restrict__ w1fg, const short* __restrict__ w2fg,
    const float* __restrict__ stats0, const float* __restrict__ stats1,
    const float* __restrict__ w0, const float* __restrict__ g0, const float* __restrict__ bb0,
    const float* __restrict__ g1, const float* __restrict__ bb1,
    float* __restrict__ stats2)
{
  __shared__ short lw0[2048];
  __shared__ short lw1[4096];
  __shared__ short lw2[8192];
  __shared__ float lsc0[64], lsf0[64], lsc1[64], lsf1[64];
  const int tid = threadIdx.x;
  for (int i = tid; i < 256; i += 256) ((int4*)lw0)[i] = ((const int4*)w0fg)[i];
  for (int i = tid; i < 512; i += 256) ((int4*)lw1)[i] = ((const int4*)w1fg)[i];
  for (int i = tid; i < 1024; i += 256) ((int4*)lw2)[i] = ((const int4*)w2fg)[i];
  if (tid < 64) bn0_dev(tid, stats0, w0, g0, bb0, lsc0, lsf0);
  else if (tid < 128) bn_dev(tid-64, 64, stats1, g1, bb1, lsc1, lsf1);
  __syncthreads();
  const int L = tid & 63, Q = L >> 4, wv = tid >> 6;
  float sc0r[4][4], sf0r[4][4];
#pragma unroll
  for (int Mt = 0; Mt < 4; ++Mt)
#pragma unroll
    for (int r = 0; r < 4; ++r) {
      const int och = 16*Mt + 4*Q + r;
      sc0r[Mt][r] = lsc0[och];
      sf0r[Mt][r] = lsf0[och];
    }
  float sS[8][4], sQ2[8][4];
#pragma unroll
  for (int Mt = 0; Mt < 8; ++Mt)
#pragma unroll
    for (int r = 0; r < 4; ++r) { sS[Mt][r] = 0.f; sQ2[Mt][r] = 0.f; }
  const int gw = blockIdx.x*4 + wv;
  for (int t = 0; t < 16; ++t) {
    const int tile = gw*16 + t;
    const bf16x8 b0 = ldf0(F0f, tile, L);
    f32x4 acc0[4];
#pragma unroll
    for (int Mt = 0; Mt < 4; ++Mt)
      acc0[Mt] = __builtin_amdgcn_mfma_f32_16x16x32_bf16(ldfrag(lw0, Mt, L), b0, ZERO4, 0, 0, 0);
    bf16x8 zf0[2];
#pragma unroll
    for (int Mt = 0; Mt < 4; ++Mt)
#pragma unroll
      for (int r = 0; r < 4; ++r) {
        const float z = fmaxf(fmaf(acc0[Mt][r], sc0r[Mt][r], sf0r[Mt][r]), 0.f);
        zf0[Mt>>1][(Mt&1)*4 + r] = f2bf(z);
      }
    f32x4 acc1[4];
#pragma unroll
    for (int Mt = 0; Mt < 4; ++Mt) {
      acc1[Mt] = __builtin_amdgcn_mfma_f32_16x16x32_bf16(ldfrag(lw1, Mt*2+0, L), zf0[0], ZERO4, 0, 0, 0);
      acc1[Mt] = __builtin_amdgcn_mfma_f32_16x16x32_bf16(ldfrag(lw1, Mt*2+1, L), zf0[1], acc1[Mt], 0, 0, 0);
    }
    bf16x8 zf1[2];
#pragma unroll
    for (int Mt = 0; Mt < 4; ++Mt)
#pragma unroll
      for (int r = 0; r < 4; ++r) {
        const int och = 16*Mt + 4*Q + r;
        const float z = fmaxf(fmaf(acc1[Mt][r], lsc1[och], lsf1[och]), 0.f);
        zf1[Mt>>1][(Mt&1)*4 + r] = f2bf(z);
      }
#pragma unroll
    for (int Mt = 0; Mt < 8; ++Mt) {
      f32x4 a2;
      a2 = __builtin_amdgcn_mfma_f32_16x16x32_bf16(ldfrag(lw2, Mt*2+0, L), zf1[0], ZERO4, 0, 0, 0);
      a2 = __builtin_amdgcn_mfma_f32_16x16x32_bf16(ldfrag(lw2, Mt*2+1, L), zf1[1], a2, 0, 0, 0);
#pragma unroll
      for (int r = 0; r < 4; ++r) {
        const float y = a2[r];
        sS[Mt][r] += y;
        sQ2[Mt][r] = fmaf(y, y, sQ2[Mt][r]);
      }
    }
  }
#pragma unroll
  for (int Mt = 0; Mt < 8; ++Mt)
#pragma unroll
    for (int r = 0; r < 4; ++r) {
#pragma unroll
      for (int off = 8; off >= 1; off >>= 1) {
        sS[Mt][r]  += __shfl_xor(sS[Mt][r], off);
        sQ2[Mt][r] += __shfl_xor(sQ2[Mt][r], off);
      }
    }
  if ((L & 15) == 0) {
#pragma unroll
    for (int Mt = 0; Mt < 8; ++Mt)
#pragma unroll
      for (int r = 0; r < 4; ++r) {
        const int och = 16*Mt + 4*Q + r;
        atomicAdd(&stats2[och], sS[Mt][r]);
        atomicAdd(&stats2[128+och], sQ2[Mt][r]);
      }
  }
}

// ---------------------------------------------------------------------------
// Pass D: full pipeline + bn2/relu + maxpool over 32 samples -> new_points.
// ---------------------------------------------------------------------------
__global__ __launch_bounds__(256, 2) void passD_kernel(
    const short* __restrict__ F0f, const short* __restrict__ w0fg,
    const short* __restrict__ w1fg, const short* __restrict__ w2fg,
    const float* __restrict__ stats0, const float* __restrict__ stats1,
    const float* __restrict__ stats2,
    const float* __restrict__ w0, const float* __restrict__ g0, const float* __restrict__ bb0,
    const float* __restrict__ g1, const float* __restrict__ bb1,
    const float* __restrict__ g2, const float* __restrict__ bb2,
    float* __restrict__ outnp)
{
  __shared__ short lw0[2048];
  __shared__ short lw1[4096];
  __shared__ short lw2[8192];
  __shared__ float lsc0[64], lsf0[64], lsc1[64], lsf1[64], lsc2[128], lsf2[128];
  const int tid = threadIdx.x;
  for (int i = tid; i < 256; i += 256) ((int4*)lw0)[i] = ((const int4*)w0fg)[i];
  for (int i = tid; i < 512; i += 256) ((int4*)lw1)[i] = ((const int4*)w1fg)[i];
  for (int i = tid; i < 1024; i += 256) ((int4*)lw2)[i] = ((const int4*)w2fg)[i];
  if (tid < 64) bn0_dev(tid, stats0, w0, g0, bb0, lsc0, lsf0);
  else if (tid < 128) bn_dev(tid-64, 64, stats1, g1, bb1, lsc1, lsf1);
  else bn_dev(tid-128, 128, stats2, g2, bb2, lsc2, lsf2);
  __syncthreads();
  const int L = tid & 63, Q = L >> 4, wv = tid >> 6;
  float sc0r[4][4], sf0r[4][4];
#pragma unroll
  for (int Mt = 0; Mt < 4; ++Mt)
#pragma unroll
    for (int r = 0; r < 4; ++r) {
      const int och = 16*Mt + 4*Q + r;
      sc0r[Mt][r] = lsc0[och];
      sf0r[Mt][r] = lsf0[och];
    }
  float m2a[8][4];
#pragma unroll
  for (int Mt = 0; Mt < 8; ++Mt)
#pragma unroll
    for (int r = 0; r < 4; ++r) m2a[Mt][r] = 0.f;
  const int gw = blockIdx.x*4 + wv;
  for (int t = 0; t < 16; ++t) {
    const int tile = gw*16 + t;
    const bf16x8 b0 = ldf0(F0f, tile, L);
    f32x4 acc0[4];
#pragma unroll
    for (int Mt = 0; Mt < 4; ++Mt)
      acc0[Mt] = __builtin_amdgcn_mfma_f32_16x16x32_bf16(ldfrag(lw0, Mt, L), b0, ZERO4, 0, 0, 0);
    bf16x8 zf0[2];
#pragma unroll
    for (int Mt = 0; Mt < 4; ++Mt)
#pragma unroll
      for (int r = 0; r < 4; ++r) {
        const float z = fmaxf(fmaf(acc0[Mt][r], sc0r[Mt][r], sf0r[Mt][r]), 0.f);
        zf0[Mt>>1][(Mt&1)*4 + r] = f2bf(z);
      }
    f32x4 acc1[4];
#pragma unroll
    for (int Mt = 0; Mt < 4; ++Mt) {
      acc1[Mt] = __builtin_amdgcn_mfma_f32_16x16x32_bf16(ldfrag(lw1, Mt*2+0, L), zf0[0], ZERO4, 0, 0, 0);
      acc1[Mt] = __builtin_amdgcn_mfma_f32_16x16x32_bf16(ldfrag(lw1, Mt*2+1, L), zf0[1], acc1[Mt], 0, 0, 0);
    }
    bf16x8 zf1[2];
#pragma unroll
    for (int Mt = 0; Mt < 4; ++Mt)
#pragma unroll
      for (int r = 0; r < 4; ++r) {
        const int och = 16*Mt + 4*Q + r;
        const float z = fmaxf(fmaf(acc1[Mt][r], lsc1[och], lsf1[och]), 0.f);
        zf1[Mt>>1][(Mt&1)*4 + r] = f2bf(z);
      }
#pragma unroll
    for (int Mt = 0; Mt < 8; ++Mt) {
      f32x4 a2;
      a2 = __builtin_amdgcn_mfma_f32_16x16x32_bf16(ldfrag(lw2, Mt*2+0, L), zf1[0], ZERO4, 0, 0, 0);
      a2 = __builtin_amdgcn_mfma_f32_16x16x32_bf16(ldfrag(lw2, Mt*2+1, L), zf1[1], a2, 0, 0, 0);
#pragma unroll
      for (int r = 0; r < 4; ++r) {
        const int och = 16*Mt + 4*Q + r;
        const float z2 = fmaxf(fmaf(a2[r], lsc2[och], lsf2[och]), 0.f);
        m2a[Mt][r] = fmaxf(m2a[Mt][r], z2);
      }
    }
    if (t & 1) {   // completed a row of 32 samples
#pragma unroll
      for (int Mt = 0; Mt < 8; ++Mt)
#pragma unroll
        for (int r = 0; r < 4; ++r) {
          float v = m2a[Mt][r];
#pragma unroll
          for (int off = 8; off >= 1; off >>= 1) v = fmaxf(v, __shfl_xor(v, off));
          m2a[Mt][r] = v;
        }
      if ((L & 15) == 0) {
        const size_t row = tile >> 1;
#pragma unroll
        for (int Mt = 0; Mt < 8; ++Mt) {
          float4 o;
          o.x = m2a[Mt][0]; o.y = m2a[Mt][1]; o.z = m2a[Mt][2]; o.w = m2a[Mt][3];
          *(float4*)&outnp[row*128 + 16*Mt + 4*Q] = o;
        }
      }
#pragma unroll
      for (int Mt = 0; Mt < 8; ++Mt)
#pragma unroll
        for (int r = 0; r < 4; ++r) m2a[Mt][r] = 0.f;
    }
  }
}

// ---------------------------------------------------------------------------
extern "C" void kernel_launch(void* const* d_in, const int* in_sizes, int n_in,
                              void* d_out, int out_size, void* d_ws, size_t ws_size,
                              hipStream_t stream)
{
  const float* xyz = (const float*)d_in[0];
  const float* pts = (const float*)d_in[1];
  const float* w0  = (const float*)d_in[2];
  const float* g0  = (const float*)d_in[4];
  const float* bb0 = (const float*)d_in[5];
  const float* w1  = (const float*)d_in[6];
  const float* g1  = (const float*)d_in[8];
  const float* bb1 = (const float*)d_in[9];
  const float* w2  = (const float*)d_in[10];
  const float* g2  = (const float*)d_in[12];
  const float* bb2 = (const float*)d_in[13];

  float* out    = (float*)d_out;
  float* newxyz = out;                     // [16,1024,3]
  float* outnp  = out + (size_t)NB*NS*3;   // [16,1024,128]

  char* ws = (char*)d_ws;
  int*   gidx = (int*)(ws);                                  // 2 MB
  short* F0f  = (short*)(ws + 2097152);                      // 16.78 MB (bf16 frags)
  char*  p    = ws + 2097152 + 16777216;
  short* w0f  = (short*)(p);            // 4096 B
  short* w1f  = (short*)(p + 4096);     // 8192 B
  short* w2f  = (short*)(p + 12288);    // 16384 B
  float* stats  = (float*)(p + 28672);
  float* stats0 = stats;              // 64 (54 used)
  float* stats1 = stats + 64;         // 128
  float* stats2 = stats + 64 + 128;   // 256
  float* pp     = (float*)(p + 28672 + 2048);  // 16x8192 f32 = 512 KB
  const size_t needed = 2097152 + 16777216 + 28672 + 2048 + (size_t)NB*NPTS*4;
  if (ws_size < needed) return;

  hipMemsetAsync(stats, 0, 448 * sizeof(float), stream);
  wfrag_prep  <<<1,     256,  0, stream>>>(w0, w1, w2, w0f, w1f, w2f);
  fps_kernel  <<<NB,    256,  0, stream>>>(xyz, newxyz, pp);
  knn_kernel  <<<16384, 64,   0, stream>>>(xyz, pp, newxyz, gidx);
  build_kernel<<<512,   256,  0, stream>>>(xyz, pts, newxyz, gidx, F0f, stats0);
  passB_kernel<<<512,   256,  0, stream>>>(F0f, w0f, w1f, stats0, w0, g0, bb0, stats1);
  passC_kernel<<<512,   256,  0, stream>>>(F0f, w0f, w1f, w2f, stats0, stats1,
                                           w0, g0, bb0, g1, bb1, stats2);
  passD_kernel<<<512,   256,  0, stream>>>(F0f, w0f, w1f, w2f, stats0, stats1, stats2,
                                           w0, g0, bb0, g1, bb1, g2, bb2, outnp);
}

// Round 16
// 1588.179 us; speedup vs baseline: 1.2423x; 1.0020x over previous
//
#include <hip/hip_runtime.h>
#include <hip/hip_bf16.h>

#define NPTS 8192
#define NB 16
#define NS 1024
#define NK 32
#define NSAMP (NB*NS*NK)  // 524288
#define NTILE (NSAMP/16)  // 32768 sample-tiles of 16
#define EPSBN 1e-5f

// Chosen k-mapping for MFMA fragments (any consistent bijection works:
// it cancels between A and B; chosen so the D->B bridge is lane-local).
#define HK(Q, JJ) (4*(Q) + ((JJ)&3) + 16*((JJ)>>2))

typedef __attribute__((ext_vector_type(8))) short bf16x8;
typedef __attribute__((ext_vector_type(4))) float f32x4;

__device__ __forceinline__ short f2bf(float x) {
  union { __hip_bfloat16 h; short s; } u;
  u.h = __float2bfloat16(x);
  return u.s;
}

// monotone float->uint mapping (preserves order for min/max on unsigned).
// REQUIRED for kNN keys: self-distance rounds to tiny NEGATIVE floats; raw
// float bits as unsigned would sort them last (R6 bug). Finite/NaN inputs
// map <= 0xFFC00000 < 0xFFFFFFFF, so ~0ull is a safe sentinel key.
__device__ __forceinline__ unsigned monof(float f) {
  unsigned u = __float_as_uint(f);
  return u ^ ((unsigned)((int)u >> 31) | 0x80000000u);
}

// ---------------------------------------------------------------------------
// Wave64 SINGLE-VALUE reductions via DPP. Each step fuses to ONE VALU op
// (v_max/min_u32 with DPP source modifier) — R12's paired (value,index)
// chain could NOT fuse (5 ops/step) and REGRESSED; do not reintroduce.
// Argmax/argmin = value chain, then masked-index min chain (exact
// smallest-index tie-break). Sequence: row_shr 1/2/4/8, row_bcast:15,
// row_bcast:31; lane 63 holds the result; readlane broadcasts.
// ---------------------------------------------------------------------------
__device__ __forceinline__ unsigned wave_max_u32(unsigned v) {
  unsigned t;
  t = (unsigned)__builtin_amdgcn_update_dpp(0, (int)v, 0x111, 0xf, 0xf, false); v = v > t ? v : t;
  t = (unsigned)__builtin_amdgcn_update_dpp(0, (int)v, 0x112, 0xf, 0xf, false); v = v > t ? v : t;
  t = (unsigned)__builtin_amdgcn_update_dpp(0, (int)v, 0x114, 0xf, 0xf, false); v = v > t ? v : t;
  t = (unsigned)__builtin_amdgcn_update_dpp(0, (int)v, 0x118, 0xf, 0xf, false); v = v > t ? v : t;
  t = (unsigned)__builtin_amdgcn_update_dpp(0, (int)v, 0x142, 0xa, 0xf, false); v = v > t ? v : t;
  t = (unsigned)__builtin_amdgcn_update_dpp(0, (int)v, 0x143, 0xc, 0xf, false); v = v > t ? v : t;
  return (unsigned)__builtin_amdgcn_readlane((int)v, 63);
}

__device__ __forceinline__ unsigned wave_min_u32(unsigned v) {
  unsigned t;
  t = (unsigned)__builtin_amdgcn_update_dpp(-1, (int)v, 0x111, 0xf, 0xf, false); v = v < t ? v : t;
  t = (unsigned)__builtin_amdgcn_update_dpp(-1, (int)v, 0x112, 0xf, 0xf, false); v = v < t ? v : t;
  t = (unsigned)__builtin_amdgcn_update_dpp(-1, (int)v, 0x114, 0xf, 0xf, false); v = v < t ? v : t;
  t = (unsigned)__builtin_amdgcn_update_dpp(-1, (int)v, 0x118, 0xf, 0xf, false); v = v < t ? v : t;
  t = (unsigned)__builtin_amdgcn_update_dpp(-1, (int)v, 0x142, 0xa, 0xf, false); v = v < t ? v : t;
  t = (unsigned)__builtin_amdgcn_update_dpp(-1, (int)v, 0x143, 0xc, 0xf, false); v = v < t ? v : t;
  return (unsigned)__builtin_amdgcn_readlane((int)v, 63);
}

// ---------------------------------------------------------------------------
// FPS (R13 exact — structural floor 855us after R9/R14 multi-wave attempts
// both regressed): 1 block/batch, 256 thr (1 wave/SIMD), xyz in LDS, LDS
// centroid accum + one flush, pp epilogue; DPP value chain + masked-index
// chain. Selection math/rounding: no-FMA, monof, smallest-idx ties.
// ---------------------------------------------------------------------------
__global__ __launch_bounds__(256, 1) void fps_kernel(
    const float* __restrict__ xyz, float* __restrict__ newxyz, float* __restrict__ pp)
{
  __shared__ float sx[NPTS*3];                 // 96 KB
  __shared__ float cs[NS*3];                   // 12 KB centroid accum
  __shared__ unsigned long long kred[2][4];
  const int b = blockIdx.x, tid = threadIdx.x;
  const float* xb = xyz + (size_t)b * NPTS * 3;
  for (int i = tid; i < NPTS*3; i += 256) sx[i] = xb[i];
  __syncthreads();
  float px[32], py[32], pz[32], dist[32];
#pragma unroll
  for (int j = 0; j < 32; ++j) {
    const int i = tid + j*256;
    px[j] = sx[3*i]; py[j] = sx[3*i+1]; pz[j] = sx[3*i+2];
    dist[j] = 1e10f;
  }
  const int wid = tid >> 6;
  int far = 0;
  for (int t = 0; t < NS; ++t) {
    const float cx = sx[3*far], cy = sx[3*far+1], cz = sx[3*far+2];
    if (tid == 0) { cs[t*3] = cx; cs[t*3+1] = cy; cs[t*3+2] = cz; }
    float bv = -1.0f; int bj = 0;
#pragma unroll
    for (int j = 0; j < 32; ++j) {
      const float dx = __fsub_rn(px[j], cx);
      const float dy = __fsub_rn(py[j], cy);
      const float dz = __fsub_rn(pz[j], cz);
      const float d = __fadd_rn(__fadd_rn(__fmul_rn(dx,dx), __fmul_rn(dy,dy)), __fmul_rn(dz,dz));
      const float dj = fminf(dist[j], d);
      dist[j] = dj;
      const bool m = dj > bv;          // j ascending -> keeps smallest idx on tie
      bv = m ? dj : bv;
      bj = m ? j : bj;
    }
    const unsigned bi = (unsigned)(tid + bj*256);
    const unsigned mv = monof(bv);
    const unsigned vmax = wave_max_u32(mv);                    // wave max value
    const unsigned mbi = (mv == vmax) ? bi : 0xFFFFFFFFu;
    const unsigned bimin = wave_min_u32(mbi);                  // smallest idx on tie
    if ((tid & 63) == 0)
      kred[t & 1][wid] = ((unsigned long long)vmax << 32) | (unsigned)(8191 - bimin);
    __syncthreads();
    unsigned long long k0 = kred[t & 1][0], k1 = kred[t & 1][1];
    unsigned long long k2 = kred[t & 1][2], k3 = kred[t & 1][3];
    k0 = (k1 > k0) ? k1 : k0;
    k2 = (k3 > k2) ? k3 : k2;
    k0 = (k2 > k0) ? k2 : k0;           // max; tie -> larger (8191-idx) = smaller idx
    far = 8191 - (int)(k0 & 0xffffffffu);
  }
  // flush centroids (coalesced) and |p|^2 epilogue (knn's exact tt rounding)
  __syncthreads();
  float* nb = newxyz + (size_t)b * NS * 3;
  for (int idx = tid; idx < NS*3; idx += 256) nb[idx] = cs[idx];
  float* ppb = pp + (size_t)b * NPTS;
#pragma unroll
  for (int j = 0; j < 32; ++j) {
    const int i = tid + j*256;
    ppb[i] = __fadd_rn(__fadd_rn(__fmul_rn(px[j],px[j]), __fmul_rn(py[j],py[j])), __fmul_rn(pz[j],pz[j]));
  }
}

// sorted insert of kk into ascending (a,b,c) triple, branch-free
#define INS3(kk, a, b, c) { \
    const bool lA = (kk) < (a), lB = (kk) < (b), lC = (kk) < (c); \
    const unsigned long long na = lA ? (kk) : (a); \
    const unsigned long long nb = lA ? (a) : (lB ? (kk) : (b)); \
    const unsigned long long nc = lB ? (b) : (lC ? (kk) : (c)); \
    (a) = na; (b) = nb; (c) = nc; }

// ---------------------------------------------------------------------------
// kNN v6 = v5 (register-resident 3-deep tournament, zero LDS, zero barriers)
// with FOUR independent query-waves per 256-thread block (grid 16384->4096:
// cuts dispatch overhead; waves never interact so semantics unchanged).
// Lane L owns i = L + 64m; 8 groups of 16 (i = L + 1024g + 64m). Fill:
// per-group ascending stack (k1,k2,k3) of packed keys (monof(d)<<32)|i.
// Per round: tree min over k1[8] -> DPP value-min chain -> masked-index min
// chain -> widx (exact smallest-index tie-break). Popped element is ALWAYS
// the owner lane's k1[g]; owner marks consumed bit, promotes (k2,k3); on
// 3rd pop since refill (~2% of rounds) recompute group keys from global
// (L2-hot) with consumed entries masked to sentinel ~0ull.
// Exactly reproduces lax.top_k(-d) order incl. smallest-index tie-break.
// ---------------------------------------------------------------------------
__global__ __launch_bounds__(256) void knn_kernel(
    const float* __restrict__ xyz, const float* __restrict__ pp,
    const float* __restrict__ newxyz, int* __restrict__ gidx)
{
  const int L = threadIdx.x & 63;
  const int row = blockIdx.x * 4 + (threadIdx.x >> 6);
  const int b = row >> 10;
  const float* xb = xyz + (size_t)b * NPTS * 3;
  const float* ppb = pp + (size_t)b * NPTS;
  const float qx = newxyz[(size_t)row*3+0];
  const float qy = newxyz[(size_t)row*3+1];
  const float qz = newxyz[(size_t)row*3+2];
  const float ss = __fadd_rn(__fadd_rn(__fmul_rn(qx,qx), __fmul_rn(qy,qy)), __fmul_rn(qz,qz));
  unsigned long long k1[8], k2[8], k3[8];
#pragma unroll
  for (int g = 0; g < 8; ++g) {
    unsigned long long a = ~0ull, bb = ~0ull, c = ~0ull;
#pragma unroll
    for (int m = 0; m < 16; ++m) {
      const int i = L + (g << 10) + (m << 6);
      const float tx = xb[3*i], ty = xb[3*i+1], tz = xb[3*i+2];
      const float tt = ppb[i];     // same bits as inline (x^2+y^2)+z^2
      const float dt = __fadd_rn(__fadd_rn(__fmul_rn(qx,tx), __fmul_rn(qy,ty)), __fmul_rn(qz,tz));
      const float d = __fadd_rn(__fadd_rn(__fmul_rn(-2.0f, dt), ss), tt);
      const unsigned long long kk = ((unsigned long long)monof(d) << 32) | (unsigned)i;
      INS3(kk, a, bb, c)
    }
    k1[g] = a; k2[g] = bb; k3[g] = c;
  }
  unsigned long long cm0 = 0, cm1 = 0;   // consumed bits: 16 per group
#pragma unroll 1
  for (int k = 0; k < NK; ++k) {
    unsigned long long a0 = k1[0] < k1[1] ? k1[0] : k1[1];
    unsigned long long a1 = k1[2] < k1[3] ? k1[2] : k1[3];
    unsigned long long a2 = k1[4] < k1[5] ? k1[4] : k1[5];
    unsigned long long a3 = k1[6] < k1[7] ? k1[6] : k1[7];
    a0 = a0 < a1 ? a0 : a1;
    a2 = a2 < a3 ? a2 : a3;
    a0 = a0 < a2 ? a0 : a2;
    const unsigned mvl = (unsigned)(a0 >> 32);
    const unsigned bil = (unsigned)a0;
    const unsigned vmin = wave_min_u32(mvl);                   // wave min value
    const unsigned mbi = (mvl == vmin) ? bil : 0xFFFFFFFFu;
    const unsigned widx = wave_min_u32(mbi);                   // smallest idx on tie
    if (L == 0) gidx[(size_t)row*NK + k] = (int)widx;
    const int g = (int)(widx >> 10);
    const int m = (int)((widx >> 6) & 15);
    const bool owner = ((widx & 63) == (unsigned)L);
    if (owner) {
      const unsigned long long bit = 1ull << (((g & 3) << 4) + m);
      if (g < 4) cm0 |= bit; else cm1 |= bit;
      // extract (k2,k3) of group g via static selects
      unsigned long long s2 = k2[0], s3 = k3[0];
#pragma unroll
      for (int gg = 1; gg < 8; ++gg) {
        s2 = (gg == g) ? k2[gg] : s2;
        s3 = (gg == g) ? k3[gg] : s3;
      }
      unsigned long long n1 = s2, n2 = s3, n3 = ~0ull;
      if (n1 == ~0ull) {                                       // rare: refill
        const unsigned msk = (unsigned)(((g < 4) ? cm0 : cm1) >> ((g & 3) << 4)) & 0xFFFFu;
        n1 = ~0ull; n2 = ~0ull; n3 = ~0ull;
#pragma unroll
        for (int m2 = 0; m2 < 16; ++m2) {
          const int i2 = L + (g << 10) + (m2 << 6);
          const float tx = xb[3*i2], ty = xb[3*i2+1], tz = xb[3*i2+2];
          const float tt = ppb[i2];
          const float dt = __fadd_rn(__fadd_rn(__fmul_rn(qx,tx), __fmul_rn(qy,ty)), __fmul_rn(qz,tz));
          const float d = __fadd_rn(__fadd_rn(__fmul_rn(-2.0f, dt), ss), tt);
          unsigned long long kk = ((unsigned long long)monof(d) << 32) | (unsigned)i2;
          kk = ((msk >> m2) & 1u) ? ~0ull : kk;                // consumed -> sentinel
          INS3(kk, n1, n2, n3)
        }
      }
#pragma unroll
      for (int gg = 0; gg < 8; ++gg) {                         // static writeback
        k1[gg] = (gg == g) ? n1 : k1[gg];
        k2[gg] = (gg == g) ? n2 : k2[gg];
        k3[gg] = (gg == g) ? n3 : k3[gg];
      }
    }
  }
}

// ---------------------------------------------------------------------------
// Build: F0 in bf16 MFMA-fragment layout F0f[tile][lane][4] (jj<4 slots; k>=9
// are zero) + f32 9-dim first/second moments for layer-0 BN stats.
// ---------------------------------------------------------------------------
__global__ __launch_bounds__(256, 4) void build_kernel(
    const float* __restrict__ xyz, const float* __restrict__ pts,
    const float* __restrict__ newxyz, const int* __restrict__ gidx,
    short* __restrict__ F0f, float* __restrict__ stats0)
{
  float m1[9];
  float m2[45];
#pragma unroll
  for (int a = 0; a < 9; ++a) m1[a] = 0.f;
#pragma unroll
  for (int c = 0; c < 45; ++c) m2[c] = 0.f;
  const int tgid = blockIdx.x * 256 + threadIdx.x;
  for (int it = 0; it < 4; ++it) {
    const int smp = tgid + it * 131072;
    const int row = smp >> 5;
    const int b = row >> 10;
    const int gi = gidx[smp];
    const float* p3 = xyz + ((size_t)b*NPTS + gi)*3;
    const float* p6 = pts + ((size_t)b*NPTS + gi)*6;
    const float* q  = newxyz + (size_t)row*3;
    float f[9];
    f[0] = __fsub_rn(p3[0], q[0]);
    f[1] = __fsub_rn(p3[1], q[1]);
    f[2] = __fsub_rn(p3[2], q[2]);
#pragma unroll
    for (int c = 0; c < 6; ++c) f[3+c] = p6[c];
    const int tile = smp >> 4, col = smp & 15;
    short4* dst = (short4*)F0f;
    short4 s0, s1, s2, s3;
    s0.x = f2bf(f[0]); s0.y = f2bf(f[1]); s0.z = f2bf(f[2]); s0.w = f2bf(f[3]);
    s1.x = f2bf(f[4]); s1.y = f2bf(f[5]); s1.z = f2bf(f[6]); s1.w = f2bf(f[7]);
    s2.x = f2bf(f[8]); s2.y = 0; s2.z = 0; s2.w = 0;
    s3.x = 0; s3.y = 0; s3.z = 0; s3.w = 0;
    dst[(size_t)tile*64 +  0 + col] = s0;
    dst[(size_t)tile*64 + 16 + col] = s1;
    dst[(size_t)tile*64 + 32 + col] = s2;
    dst[(size_t)tile*64 + 48 + col] = s3;
    int cnt = 0;
#pragma unroll
    for (int a = 0; a < 9; ++a) {
      m1[a] += f[a];
#pragma unroll
      for (int b2 = a; b2 < 9; ++b2) { m2[cnt] = fmaf(f[a], f[b2], m2[cnt]); ++cnt; }
    }
  }
#pragma unroll
  for (int off = 32; off >= 1; off >>= 1) {
#pragma unroll
    for (int a = 0; a < 9; ++a) m1[a] += __shfl_xor(m1[a], off);
#pragma unroll
    for (int c = 0; c < 45; ++c) m2[c] += __shfl_xor(m2[c], off);
  }
  __shared__ float sred[4][54];
  const int wid = threadIdx.x >> 6;
  if ((threadIdx.x & 63) == 0) {
#pragma unroll
    for (int a = 0; a < 9; ++a) sred[wid][a] = m1[a];
#pragma unroll
    for (int c = 0; c < 45; ++c) sred[wid][9+c] = m2[c];
  }
  __syncthreads();
  if (threadIdx.x < 54) {
    const float v = sred[0][threadIdx.x] + sred[1][threadIdx.x] +
                    sred[2][threadIdx.x] + sred[3][threadIdx.x];
    atomicAdd(&stats0[threadIdx.x], v);
  }
}

// ---------------------------------------------------------------------------
// In-block weight-fragment staging (replaces wfrag_prep kernel: one fewer
// launch; weights are tiny & L1/L2-hot, computed once per block).
// lw0: 4 frags (Mt, K=32 zero-padded past 9). lw1: 8 (Mt*2+ks). lw2: 16.
// ---------------------------------------------------------------------------
__device__ __forceinline__ void stage_wfrags(int tid,
    const float* __restrict__ w0, const float* __restrict__ w1,
    const float* __restrict__ w2,
    short* __restrict__ lw0, short* __restrict__ lw1, short* __restrict__ lw2)
{
  {
    const int it = tid;                       // 256 entries (4*64)
    const int Mt = it >> 6, L = it & 63, Q = L >> 4, col = L & 15;
    short* dst = &lw0[it*8];
#pragma unroll
    for (int jj = 0; jj < 8; ++jj) {
      const int k = HK(Q, jj);
      dst[jj] = (k < 9) ? f2bf(w0[(16*Mt + col)*9 + k]) : (short)0;
    }
  }
#pragma unroll
  for (int r = 0; r < 2; ++r) {
    const int it = tid + r*256;               // 512 entries (8*64)
    const int fi = it >> 6, L = it & 63, Q = L >> 4, col = L & 15;
    const int Mt = fi >> 1, ks = fi & 1;
    short* dst = &lw1[it*8];
#pragma unroll
    for (int jj = 0; jj < 8; ++jj)
      dst[jj] = f2bf(w1[(16*Mt + col)*64 + 32*ks + HK(Q, jj)]);
  }
  if (lw2) {
#pragma unroll
    for (int r = 0; r < 4; ++r) {
      const int it = tid + r*256;             // 1024 entries (16*64)
      const int fi = it >> 6, L = it & 63, Q = L >> 4, col = L & 15;
      const int Mt = fi >> 1, ks = fi & 1;
      short* dst = &lw2[it*8];
#pragma unroll
      for (int jj = 0; jj < 8; ++jj)
        dst[jj] = f2bf(w2[(16*Mt + col)*64 + 32*ks + HK(Q, jj)]);
    }
  }
}

// ---------------------------------------------------------------------------
// BN param device helpers (deterministic; recomputed per block).
// ---------------------------------------------------------------------------
__device__ __forceinline__ void bn0_dev(int c, const float* __restrict__ stats0,
    const float* __restrict__ w0, const float* __restrict__ g0,
    const float* __restrict__ bb0, float* __restrict__ sc, float* __restrict__ sf)
{
  const float invn = 1.0f / (float)NSAMP;
  float wv[9];
#pragma unroll
  for (int a = 0; a < 9; ++a) wv[a] = w0[c*9+a];
  float tm = 0.f;
#pragma unroll
  for (int a = 0; a < 9; ++a) tm = fmaf(wv[a], stats0[a], tm);
  float q = 0.f;
  int cnt = 9;
#pragma unroll
  for (int a = 0; a < 9; ++a) {
#pragma unroll
    for (int b2 = a; b2 < 9; ++b2) {
      const float coef = (a == b2) ? (wv[a]*wv[a]) : (2.f*wv[a]*wv[b2]);
      q = fmaf(coef, stats0[cnt], q);
      ++cnt;
    }
  }
  const float mean = tm * invn;
  const float var = q * invn - mean*mean;
  const float scale = g0[c] / sqrtf(var + EPSBN);
  sc[c] = scale;
  sf[c] = fmaf(-mean, scale, bb0[c]);
}

__device__ __forceinline__ void bn_dev(int c, int C, const float* __restrict__ sums,
    const float* __restrict__ g, const float* __restrict__ bb,
    float* __restrict__ sc, float* __restrict__ sf)
{
  const float invn = 1.0f / (float)NSAMP;
  const float mean = sums[c] * invn;
  const float var = sums[C + c] * invn - mean*mean;
  const float scale = g[c] / sqrtf(var + EPSBN);
  sc[c] = scale;
  sf[c] = fmaf(-mean, scale, bb[c]);
}

// ---------------------------------------------------------------------------
// MFMA pass helpers (D layout verified: n=lane&15, m=16*Mt+4*(lane>>4)+reg).
// ---------------------------------------------------------------------------
#define ZERO4 (f32x4){0.f,0.f,0.f,0.f}

__device__ __forceinline__ bf16x8 ldfrag(const short* p, int fi, int L) {
  return ((const bf16x8*)p)[fi*64 + L];
}

__device__ __forceinline__ bf16x8 ldf0(const short* __restrict__ F0f, int tile, int L) {
  const short4 v = ((const short4*)F0f)[(size_t)tile*64 + L];
  bf16x8 b = {0,0,0,0,0,0,0,0};
  b[0] = v.x; b[1] = v.y; b[2] = v.z; b[3] = v.w;
  return b;
}

// ---------------------------------------------------------------------------
// Pass B: GEMM0 -> bn0/relu -> GEMM1 raw; accumulate sum/sumsq per och1.
// Weight frags + bn0 computed in-block.
// ---------------------------------------------------------------------------
__global__ __launch_bounds__(256, 3) void passB_kernel(
    const short* __restrict__ F0f, const float* __restrict__ stats0,
    const float* __restrict__ w0, const float* __restrict__ w1,
    const float* __restrict__ g0, const float* __restrict__ bb0,
    float* __restrict__ stats1)
{
  __shared__ short lw0[2048];
  __shared__ short lw1[4096];
  __shared__ float lsc0[64], lsf0[64];
  const int tid = threadIdx.x;
  stage_wfrags(tid, w0, w1, nullptr, lw0, lw1, nullptr);
  if (tid < 64) bn0_dev(tid, stats0, w0, g0, bb0, lsc0, lsf0);
  __syncthreads();
  const int L = tid & 63, Q = L >> 4, wv = tid >> 6;
  float sc0r[4][4], sf0r[4][4];
#pragma unroll
  for (int Mt = 0; Mt < 4; ++Mt)
#pragma unroll
    for (int r = 0; r < 4; ++r) {
      const int och = 16*Mt + 4*Q + r;
      sc0r[Mt][r] = lsc0[och];
      sf0r[Mt][r] = lsf0[och];
    }
  float sS[4][4], sQ2[4][4];
#pragma unroll
  for (int Mt = 0; Mt < 4; ++Mt)
#pragma unroll
    for (int r = 0; r < 4; ++r) { sS[Mt][r] = 0.f; sQ2[Mt][r] = 0.f; }
  const int gw = blockIdx.x*4 + wv;
  for (int t = 0; t < 16; ++t) {
    const int tile = gw*16 + t;
    const bf16x8 b0 = ldf0(F0f, tile, L);
    f32x4 acc0[4];
#pragma unroll
    for (int Mt = 0; Mt < 4; ++Mt)
      acc0[Mt] = __builtin_amdgcn_mfma_f32_16x16x32_bf16(ldfrag(lw0, Mt, L), b0, ZERO4, 0, 0, 0);
    bf16x8 zf[2];
#pragma unroll
    for (int Mt = 0; Mt < 4; ++Mt)
#pragma unroll
      for (int r = 0; r < 4; ++r) {
        const float z = fmaxf(fmaf(acc0[Mt][r], sc0r[Mt][r], sf0r[Mt][r]), 0.f);
        zf[Mt>>1][(Mt&1)*4 + r] = f2bf(z);
      }
    f32x4 acc1[4];
#pragma unroll
    for (int Mt = 0; Mt < 4; ++Mt) {
      acc1[Mt] = __builtin_amdgcn_mfma_f32_16x16x32_bf16(ldfrag(lw1, Mt*2+0, L), zf[0], ZERO4, 0, 0, 0);
      acc1[Mt] = __builtin_amdgcn_mfma_f32_16x16x32_bf16(ldfrag(lw1, Mt*2+1, L), zf[1], acc1[Mt], 0, 0, 0);
    }
#pragma unroll
    for (int Mt = 0; Mt < 4; ++Mt)
#pragma unroll
      for (int r = 0; r < 4; ++r) {
        const float y = acc1[Mt][r];
        sS[Mt][r] += y;
        sQ2[Mt][r] = fmaf(y, y, sQ2[Mt][r]);
      }
  }
#pragma unroll
  for (int Mt = 0; Mt < 4; ++Mt)
#pragma unroll
    for (int r = 0; r < 4; ++r) {
#pragma unroll
      for (int off = 8; off >= 1; off >>= 1) {
        sS[Mt][r]  += __shfl_xor(sS[Mt][r], off);
        sQ2[Mt][r] += __shfl_xor(sQ2[Mt][r], off);
      }
    }
  if ((L & 15) == 0) {
#pragma unroll
    for (int Mt = 0; Mt < 4; ++Mt)
#pragma unroll
      for (int r = 0; r < 4; ++r) {
        const int och = 16*Mt + 4*Q + r;
        atomicAdd(&stats1[och], sS[Mt][r]);
        atomicAdd(&stats1[64+och], sQ2[Mt][r]);
      }
  }
}

// ---------------------------------------------------------------------------
// Pass C: GEMM0 -> GEMM1 -> GEMM2 raw; accumulate sum/sumsq per och2.
// Weight frags + bn0/bn1 computed in-block.
// ---------------------------------------------------------------------------
__global__ __launch_bounds__(256, 2) void passC_kernel(
    const short* __restrict__ F0f,
    const float* __restrict__ stats0, const float* __restrict__ stats1,
    const float* __restrict__ w0, const float* __restrict__ w1, const float* __restrict__ w2,
    const float* __restrict__ g0, const float* __restrict__ bb0,
    const float* __restrict__ g1, const float* __restrict__ bb1,
    float* __restrict__ stats2)
{
  __shared__ short lw0[2048];
  __shared__ short lw1[4096];
  __shared__ short lw2[8192];
  __shared__ float lsc0[64], lsf0[64], lsc1[64], lsf1[64];
  const int tid = threadIdx.x;
  stage_wfrags(tid, w0, w1, w2, lw0, lw1, lw2);
  if (tid < 64) bn0_dev(tid, stats0, w0, g0, bb0, lsc0, lsf0);
  else if (tid < 128) bn_dev(tid-64, 64, stats1, g1, bb1, lsc1, lsf1);
  __syncthreads();
  const int L = tid & 63, Q = L >> 4, wv = tid >> 6;
  float sc0r[4][4], sf0r[4][4];
#pragma unroll
  for (int Mt = 0; Mt < 4; ++Mt)
#pragma unroll
    for (int r = 0; r < 4; ++r) {
      const int och = 16*Mt + 4*Q + r;
      sc0r[Mt][r] = lsc0[och];
      sf0r[Mt][r] = lsf0[och];
    }
  float sS[8][4], sQ2[8][4];
#pragma unroll
  for (int Mt = 0; Mt < 8; ++Mt)
#pragma unroll
    for (int r = 0; r < 4; ++r) { sS[Mt][r] = 0.f; sQ2[Mt][r] = 0.f; }
  const int gw = blockIdx.x*4 + wv;
  for (int t = 0; t < 16; ++t) {
    const int tile = gw*16 + t;
    const bf16x8 b0 = ldf0(F0f, tile, L);
    f32x4 acc0[4];
#pragma unroll
    for (int Mt = 0; Mt < 4; ++Mt)
      acc0[Mt] = __builtin_amdgcn_mfma_f32_16x16x32_bf16(ldfrag(lw0, Mt, L), b0, ZERO4, 0, 0, 0);
    bf16x8 zf0[2];
#pragma unroll
    for (int Mt = 0; Mt < 4; ++Mt)
#pragma unroll
      for (int r = 0; r < 4; ++r) {
        const float z = fmaxf(fmaf(acc0[Mt][r], sc0r[Mt][r], sf0r[Mt][r]), 0.f);
        zf0[Mt>>1][(Mt&1)*4 + r] = f2bf(z);
      }
    f32x4 acc1[4];
#pragma unroll
    for (int Mt = 0; Mt < 4; ++Mt) {
      acc1[Mt] = __builtin_amdgcn_mfma_f32_16x16x32_bf16(ldfrag(lw1, Mt*2+0, L), zf0[0], ZERO4, 0, 0, 0);
      acc1[Mt] = __builtin_amdgcn_mfma_f32_16x16x32_bf16(ldfrag(lw1, Mt*2+1, L), zf0[1], acc1[Mt], 0, 0, 0);
    }
    bf16x8 zf1[2];
#pragma unroll
    for (int Mt = 0; Mt < 4; ++Mt)
#pragma unroll
      for (int r = 0; r < 4; ++r) {
        const int och = 16*Mt + 4*Q + r;
        const float z = fmaxf(fmaf(acc1[Mt][r], lsc1[och], lsf1[och]), 0.f);
        zf1[Mt>>1][(Mt&1)*4 + r] = f2bf(z);
      }
#pragma unroll
    for (int Mt = 0; Mt < 8; ++Mt) {
      f32x4 a2;
      a2 = __builtin_amdgcn_mfma_f32_16x16x32_bf16(ldfrag(lw2, Mt*2+0, L), zf1[0], ZERO4, 0, 0, 0);
      a2 = __builtin_amdgcn_mfma_f32_16x16x32_bf16(ldfrag(lw2, Mt*2+1, L), zf1[1], a2, 0, 0, 0);
#pragma unroll
      for (int r = 0; r < 4; ++r) {
        const float y = a2[r];
        sS[Mt][r] += y;
        sQ2[Mt][r] = fmaf(y, y, sQ2[Mt][r]);
      }
    }
  }
#pragma unroll
  for (int Mt = 0; Mt < 8; ++Mt)
#pragma unroll
    for (int r = 0; r < 4; ++r) {
#pragma unroll
      for (int off = 8; off >= 1; off >>= 1) {
        sS[Mt][r]  += __shfl_xor(sS[Mt][r], off);
        sQ2[Mt][r] += __shfl_xor(sQ2[Mt][r], off);
      }
    }
  if ((L & 15) == 0) {
#pragma unroll
    for (int Mt = 0; Mt < 8; ++Mt)
#pragma unroll
      for (int r = 0; r < 4; ++r) {
        const int och = 16*Mt + 4*Q + r;
        atomicAdd(&stats2[och], sS[Mt][r]);
        atomicAdd(&stats2[128+och], sQ2[Mt][r]);
      }
  }
}

// ---------------------------------------------------------------------------
// Pass D: full pipeline + bn2/relu + maxpool over 32 samples -> new_points.
// Weight frags + bn0/bn1/bn2 computed in-block.
// ---------------------------------------------------------------------------
__global__ __launch_bounds__(256, 2) void passD_kernel(
    const short* __restrict__ F0f,
    const float* __restrict__ stats0, const float* __restrict__ stats1,
    const float* __restrict__ stats2,
    const float* __restrict__ w0, const float* __restrict__ w1, const float* __restrict__ w2,
    const float* __restrict__ g0, const float* __restrict__ bb0,
    const float* __restrict__ g1, const float* __restrict__ bb1,
    const float* __restrict__ g2, const float* __restrict__ bb2,
    float* __restrict__ outnp)
{
  __shared__ short lw0[2048];
  __shared__ short lw1[4096];
  __shared__ short lw2[8192];
  __shared__ float lsc0[64], lsf0[64], lsc1[64], lsf1[64], lsc2[128], lsf2[128];
  const int tid = threadIdx.x;
  stage_wfrags(tid, w0, w1, w2, lw0, lw1, lw2);
  if (tid < 64) bn0_dev(tid, stats0, w0, g0, bb0, lsc0, lsf0);
  else if (tid < 128) bn_dev(tid-64, 64, stats1, g1, bb1, lsc1, lsf1);
  else bn_dev(tid-128, 128, stats2, g2, bb2, lsc2, lsf2);
  __syncthreads();
  const int L = tid & 63, Q = L >> 4, wv = tid >> 6;
  float sc0r[4][4], sf0r[4][4];
#pragma unroll
  for (int Mt = 0; Mt < 4; ++Mt)
#pragma unroll
    for (int r = 0; r < 4; ++r) {
      const int och = 16*Mt + 4*Q + r;
      sc0r[Mt][r] = lsc0[och];
      sf0r[Mt][r] = lsf0[och];
    }
  float m2a[8][4];
#pragma unroll
  for (int Mt = 0; Mt < 8; ++Mt)
#pragma unroll
    for (int r = 0; r < 4; ++r) m2a[Mt][r] = 0.f;
  const int gw = blockIdx.x*4 + wv;
  for (int t = 0; t < 16; ++t) {
    const int tile = gw*16 + t;
    const bf16x8 b0 = ldf0(F0f, tile, L);
    f32x4 acc0[4];
#pragma unroll
    for (int Mt = 0; Mt < 4; ++Mt)
      acc0[Mt] = __builtin_amdgcn_mfma_f32_16x16x32_bf16(ldfrag(lw0, Mt, L), b0, ZERO4, 0, 0, 0);
    bf16x8 zf0[2];
#pragma unroll
    for (int Mt = 0; Mt < 4; ++Mt)
#pragma unroll
      for (int r = 0; r < 4; ++r) {
        const float z = fmaxf(fmaf(acc0[Mt][r], sc0r[Mt][r], sf0r[Mt][r]), 0.f);
        zf0[Mt>>1][(Mt&1)*4 + r] = f2bf(z);
      }
    f32x4 acc1[4];
#pragma unroll
    for (int Mt = 0; Mt < 4; ++Mt) {
      acc1[Mt] = __builtin_amdgcn_mfma_f32_16x16x32_bf16(ldfrag(lw1, Mt*2+0, L), zf0[0], ZERO4, 0, 0, 0);
      acc1[Mt] = __builtin_amdgcn_mfma_f32_16x16x32_bf16(ldfrag(lw1, Mt*2+1, L), zf0[1], acc1[Mt], 0, 0, 0);
    }
    bf16x8 zf1[2];
#pragma unroll
    for (int Mt = 0; Mt < 4; ++Mt)
#pragma unroll
      for (int r = 0; r < 4; ++r) {
        const int och = 16*Mt + 4*Q + r;
        const float z = fmaxf(fmaf(acc1[Mt][r], lsc1[och], lsf1[och]), 0.f);
        zf1[Mt>>1][(Mt&1)*4 + r] = f2bf(z);
      }
#pragma unroll
    for (int Mt = 0; Mt < 8; ++Mt) {
      f32x4 a2;
      a2 = __builtin_amdgcn_mfma_f32_16x16x32_bf16(ldfrag(lw2, Mt*2+0, L), zf1[0], ZERO4, 0, 0, 0);
      a2 = __builtin_amdgcn_mfma_f32_16x16x32_bf16(ldfrag(lw2, Mt*2+1, L), zf1[1], a2, 0, 0, 0);
#pragma unroll
      for (int r = 0; r < 4; ++r) {
        const int och = 16*Mt + 4*Q + r;
        const float z2 = fmaxf(fmaf(a2[r], lsc2[och], lsf2[och]), 0.f);
        m2a[Mt][r] = fmaxf(m2a[Mt][r], z2);
      }
    }
    if (t & 1) {   // completed a row of 32 samples
#pragma unroll
      for (int Mt = 0; Mt < 8; ++Mt)
#pragma unroll
        for (int r = 0; r < 4; ++r) {
          float v = m2a[Mt][r];
#pragma unroll
          for (int off = 8; off >= 1; off >>= 1) v = fmaxf(v, __shfl_xor(v, off));
          m2a[Mt][r] = v;
        }
      if ((L & 15) == 0) {
        const size_t row = tile >> 1;
#pragma unroll
        for (int Mt = 0; Mt < 8; ++Mt) {
          float4 o;
          o.x = m2a[Mt][0]; o.y = m2a[Mt][1]; o.z = m2a[Mt][2]; o.w = m2a[Mt][3];
          *(float4*)&outnp[row*128 + 16*Mt + 4*Q] = o;
        }
      }
#pragma unroll
      for (int Mt = 0; Mt < 8; ++Mt)
#pragma unroll
        for (int r = 0; r < 4; ++r) m2a[Mt][r] = 0.f;
    }
  }
}

// ---------------------------------------------------------------------------
extern "C" void kernel_launch(void* const* d_in, const int* in_sizes, int n_in,
                              void* d_out, int out_size, void* d_ws, size_t ws_size,
                              hipStream_t stream)
{
  const float* xyz = (const float*)d_in[0];
  const float* pts = (const float*)d_in[1];
  const float* w0  = (const float*)d_in[2];
  const float* g0  = (const float*)d_in[4];
  const float* bb0 = (const float*)d_in[5];
  const float* w1  = (const float*)d_in[6];
  const float* g1  = (const float*)d_in[8];
  const float* bb1 = (const float*)d_in[9];
  const float* w2  = (const float*)d_in[10];
  const float* g2  = (const float*)d_in[12];
  const float* bb2 = (const float*)d_in[13];

  float* out    = (float*)d_out;
  float* newxyz = out;                     // [16,1024,3]
  float* outnp  = out + (size_t)NB*NS*3;   // [16,1024,128]

  char* ws = (char*)d_ws;
  int*   gidx = (int*)(ws);                                  // 2 MB
  short* F0f  = (short*)(ws + 2097152);                      // 16.78 MB (bf16 frags)
  char*  p    = ws + 2097152 + 16777216;
  float* stats  = (float*)(p);
  float* stats0 = stats;              // 64 (54 used)
  float* stats1 = stats + 64;         // 128
  float* stats2 = stats + 64 + 128;   // 256
  float* pp     = (float*)(p + 2048); // 16x8192 f32 = 512 KB
  const size_t needed = 2097152 + 16777216 + 2048 + (size_t)NB*NPTS*4;
  if (ws_size < needed) return;

  hipMemsetAsync(stats, 0, 448 * sizeof(float), stream);
  fps_kernel  <<<NB,    256,  0, stream>>>(xyz, newxyz, pp);
  knn_kernel  <<<4096,  256,  0, stream>>>(xyz, pp, newxyz, gidx);
  build_kernel<<<512,   256,  0, stream>>>(xyz, pts, newxyz, gidx, F0f, stats0);
  passB_kernel<<<512,   256,  0, stream>>>(F0f, stats0, w0, w1, g0, bb0, stats1);
  passC_kernel<<<512,   256,  0, stream>>>(F0f, stats0, stats1, w0, w1, w2,
                                           g0, bb0, g1, bb1, stats2);
  passD_kernel<<<512,   256,  0, stream>>>(F0f, stats0, stats1, stats2, w0, w1, w2,
                                           g0, bb0, g1, bb1, g2, bb2, outnp);
}